// Round 7
// baseline (268.224 us; speedup 1.0000x reference)
//
#include <hip/hip_runtime.h>
#include <math.h>

// Problem constants (from reference)
#define KK     500   // info bits
#define MM     500   // parity checks
#define NNODES 1000  // N = K + M variable nodes
#define NSYM   250   // N / BPS
#define NITERS 5
#define MAXVDEG 4    // info vars degree exactly 3 (row weight of P), parity vars 1
#define EMAX   2048  // E = 2000 edges; slot EMAX-1 is the永-zero dummy sibling
#define DUMMY  (EMAX - 1)
#define TB     256

// ---------------- bit packing ----------------
__global__ void __launch_bounds__(256) k_pack_P(const int* __restrict__ P, unsigned* __restrict__ Ppack) {
  int id = blockIdx.x * blockDim.x + threadIdx.x;
  if (id >= MM * 16) return;
  int j = id >> 4, w = id & 15;
  unsigned word = 0u;
  int base = w * 32;
  for (int bit = 0; bit < 32; ++bit) {
    int i = base + bit;
    if (i < KK && P[i * MM + j] != 0) word |= (1u << bit);
  }
  Ppack[j * 16 + w] = word;
}

__global__ void __launch_bounds__(256) k_pack_b(const int* __restrict__ b, unsigned* __restrict__ bpack, int ncw) {
  int id = blockIdx.x * blockDim.x + threadIdx.x;
  if (id >= ncw * 16) return;
  int cw = id >> 4, w = id & 15;
  unsigned word = 0u;
  int base = w * 32;
  for (int bit = 0; bit < 32; ++bit) {
    int i = base + bit;
    if (i < KK && b[cw * KK + i] != 0) word |= (1u << bit);
  }
  bpack[cw * 16 + w] = word;
}

// ---------------- symbol indices, layout [bt][s][ue] ----------------
__global__ void __launch_bounds__(256) k_sym(const unsigned* __restrict__ bpack, const unsigned* __restrict__ Ppack,
                                             int* __restrict__ symidx2, int ncw) {
  int id = blockIdx.x * blockDim.x + threadIdx.x;
  if (id >= ncw * NSYM) return;
  int cw = id / NSYM, s = id - cw * NSYM;
  int idx = 0;
  #pragma unroll
  for (int k = 0; k < 4; ++k) {
    int n = 4 * s + k;
    int bit;
    if (n < KK) {
      bit = (bpack[cw * 16 + (n >> 5)] >> (n & 31)) & 1;
    } else {
      int j = n - KK;
      int cnt = 0;
      #pragma unroll
      for (int w = 0; w < 16; ++w) cnt += __popc(bpack[cw * 16 + w] & Ppack[j * 16 + w]);
      bit = cnt & 1;
    }
    idx = (idx << 1) | bit;  // MSB-first: weights 8,4,2,1
  }
  symidx2[(((cw >> 2) * NSYM) + s) * 4 + (cw & 3)] = idx;
}

// ---------------- output 0: bf = float(b) ----------------
__global__ void __launch_bounds__(256) k_bf(const int* __restrict__ b, float* __restrict__ out, int n) {
  int id = blockIdx.x * blockDim.x + threadIdx.x;
  if (id < n) out[id] = (float)b[id];
}

// ---------------- noise variance (once, not 250k fp64 pow calls) ----------
__global__ void k_no(const float* __restrict__ ebno, double* __restrict__ nobuf) {
  double no = 1.0 / (pow(10.0, (double)ebno[0] * 0.1) * 2.0);  // BPS*RATE = 2
  nobuf[0] = no;
  nobuf[1] = sqrt(no * 0.5);
}

// ---------------- graph build: count -> scan -> fill -> siblings ----------
__global__ void __launch_bounds__(256) k_count(const int* __restrict__ cn, int E, int* __restrict__ cdeg) {
  int e = blockIdx.x * blockDim.x + threadIdx.x;
  if (e < E) atomicAdd(&cdeg[cn[e]], 1);
}

__global__ void __launch_bounds__(512) k_scan(const int* __restrict__ cdeg,
                                              int* __restrict__ coff, int* __restrict__ cur) {
  __shared__ int s[512];
  int tid = threadIdx.x;
  int v = (tid < MM) ? cdeg[tid] : 0;
  s[tid] = v;
  __syncthreads();
  for (int o = 1; o < 512; o <<= 1) {
    int x = (tid >= o) ? s[tid - o] : 0;
    __syncthreads();
    s[tid] += x;
    __syncthreads();
  }
  if (tid < MM) {
    int excl = s[tid] - v;
    coff[tid] = excl;
    cur[tid]  = excl;
    if (tid == MM - 1) coff[MM] = s[tid];
  }
}

__global__ void __launch_bounds__(256) k_fill2(const int* __restrict__ cn, const int* __restrict__ vn, int E,
                                               int* __restrict__ cur, int* __restrict__ cinfo,
                                               int* __restrict__ vdeg, int* __restrict__ vlist) {
  int e = blockIdx.x * blockDim.x + threadIdx.x;
  if (e >= E) return;
  int c = cn[e], n = vn[e];
  int slot = atomicAdd(&cur[c], 1);
  cinfo[slot] = (c << 16) | n;
  int t = atomicAdd(&vdeg[n], 1);
  if (t < MAXVDEG) vlist[n * MAXVDEG + t] = slot;
}

// per-edge sibling slots: the OTHER edges at the same var node.
// deg-3 info node -> two real siblings; deg-1 parity node -> dummy zero slot.
__global__ void __launch_bounds__(256) k_sib(const int* __restrict__ cinfo, const int* __restrict__ vdeg,
                                             const int* __restrict__ vlist, int E, int* __restrict__ esib) {
  int e = blockIdx.x * blockDim.x + threadIdx.x;
  if (e >= E) return;
  int n = cinfo[e] & 0xffff;
  int a = DUMMY, b = DUMMY;
  if (vdeg[n] == 3) {
    int s0 = vlist[n * MAXVDEG], s1 = vlist[n * MAXVDEG + 1], s2 = vlist[n * MAXVDEG + 2];
    if (e == s0)      { a = s1; b = s2; }
    else if (e == s1) { a = s0; b = s2; }
    else              { a = s0; b = s1; }
  }
  esib[e] = (a << 16) | b;
}

// ---------------- 16-QAM constellation (fp64 for TX symbol) ----------------
__device__ __forceinline__ void qam_point(int p, double& re, double& im) {
  const double s = 0.31622776601683794;  // 1/sqrt(10)
  int b0 = (p >> 3) & 1, b1 = (p >> 2) & 1, b2 = (p >> 1) & 1, b3 = p & 1;
  re = (double)((1 - 2 * b0) * (2 - (1 - 2 * b2))) * s;
  im = (double)((1 - 2 * b1) * (2 - (1 - 2 * b3))) * s;
}

// ---------------- channel + LMMSE + max-log LLR --------------------------
// fp64 channel/Cholesky/solve (scalarized lower-triangular L); fp32 demap.
// Output Lch3[bt][pair][node][2]: contiguous float2 per codeword-pair.
__global__ void __launch_bounds__(256, 1)
k_lmmse(const float* __restrict__ h_re, const float* __restrict__ h_im,
        const float* __restrict__ n_re, const float* __restrict__ n_im,
        const double* __restrict__ nobuf, const int* __restrict__ symidx2,
        float* __restrict__ Lch3, int T, int ncw) {
  int t = blockIdx.x * blockDim.x + threadIdx.x;
  if (t >= T) return;
  int bt = t / NSYM, s = t - bt * NSYM;

  double no = nobuf[0];
  double sq = nobuf[1];
  const double is2 = 0.7071067811865475244;  // 1/sqrt(2)

  double Hr[4][4], Hi[4][4];
  {
    const float4* hr4 = (const float4*)h_re;
    const float4* hi4 = (const float4*)h_im;
    #pragma unroll
    for (int i = 0; i < 4; ++i) {
      float4 a = hr4[t * 4 + i], c = hi4[t * 4 + i];
      Hr[i][0] = (double)a.x * is2; Hr[i][1] = (double)a.y * is2;
      Hr[i][2] = (double)a.z * is2; Hr[i][3] = (double)a.w * is2;
      Hi[i][0] = (double)c.x * is2; Hi[i][1] = (double)c.y * is2;
      Hi[i][2] = (double)c.z * is2; Hi[i][3] = (double)c.w * is2;
    }
  }

  double xr[4], xi[4];
  {
    int4 ss = ((const int4*)symidx2)[bt * NSYM + s];
    qam_point(ss.x, xr[0], xi[0]);
    qam_point(ss.y, xr[1], xi[1]);
    qam_point(ss.z, xr[2], xi[2]);
    qam_point(ss.w, xr[3], xi[3]);
  }

  // y = H x + w
  double yr[4], yi[4];
  {
    float4 wr = ((const float4*)n_re)[t];
    float4 wi = ((const float4*)n_im)[t];
    float wrv[4] = {wr.x, wr.y, wr.z, wr.w};
    float wiv[4] = {wi.x, wi.y, wi.z, wi.w};
    #pragma unroll
    for (int i = 0; i < 4; ++i) {
      double ar = (double)wrv[i] * sq;
      double ai = (double)wiv[i] * sq;
      #pragma unroll
      for (int j = 0; j < 4; ++j) {
        ar += Hr[i][j] * xr[j] - Hi[i][j] * xi[j];
        ai += Hr[i][j] * xi[j] + Hi[i][j] * xr[j];
      }
      yr[i] = ar; yi[i] = ai;
    }
  }

  // A = H H^H + no I, lower triangle, into scalars
  auto dotc = [&](int i, int j, double& ar, double& ai) {
    double r = 0.0, m = 0.0;
    #pragma unroll
    for (int k = 0; k < 4; ++k) {
      r += Hr[i][k] * Hr[j][k] + Hi[i][k] * Hi[j][k];
      m += Hi[i][k] * Hr[j][k] - Hr[i][k] * Hi[j][k];
    }
    ar = r; ai = m;
  };
  double a00, a11, a22, a33, dum;
  double a10r, a10i, a20r, a20i, a21r, a21i, a30r, a30i, a31r, a31i, a32r, a32i;
  dotc(0, 0, a00, dum);  a00 += no;
  dotc(1, 0, a10r, a10i);
  dotc(1, 1, a11, dum);  a11 += no;
  dotc(2, 0, a20r, a20i);
  dotc(2, 1, a21r, a21i);
  dotc(2, 2, a22, dum);  a22 += no;
  dotc(3, 0, a30r, a30i);
  dotc(3, 1, a31r, a31i);
  dotc(3, 2, a32r, a32i);
  dotc(3, 3, a33, dum);  a33 += no;

  // Cholesky A = L L^H (scalarized)
  double L00 = sqrt(a00);
  double i00 = 1.0 / L00;
  double L10r = a10r * i00, L10i = a10i * i00;
  double L20r = a20r * i00, L20i = a20i * i00;
  double L30r = a30r * i00, L30i = a30i * i00;
  double L11 = sqrt(a11 - (L10r * L10r + L10i * L10i));
  double i11 = 1.0 / L11;
  double L21r = (a21r - (L20r * L10r + L20i * L10i)) * i11;
  double L21i = (a21i - (L20i * L10r - L20r * L10i)) * i11;
  double L31r = (a31r - (L30r * L10r + L30i * L10i)) * i11;
  double L31i = (a31i - (L30i * L10r - L30r * L10i)) * i11;
  double L22 = sqrt(a22 - (L20r * L20r + L20i * L20i) - (L21r * L21r + L21i * L21i));
  double i22 = 1.0 / L22;
  double L32r = (a32r - (L30r * L20r + L30i * L20i) - (L31r * L21r + L31i * L21i)) * i22;
  double L32i = (a32i - (L30i * L20r - L30r * L20i) - (L31i * L21r - L31r * L21i)) * i22;
  double L33 = sqrt(a33 - (L30r * L30r + L30i * L30i) - (L31r * L31r + L31i * L31i)
                        - (L32r * L32r + L32i * L32i));
  double i33 = 1.0 / L33;

  // forward solve: U = L^{-1} H (in place on H), v = L^{-1} y (in place on y)
  #pragma unroll
  for (int j = 0; j < 4; ++j) {
    double u0r = Hr[0][j] * i00,               u0i = Hi[0][j] * i00;
    double u1r = (Hr[1][j] - (L10r * u0r - L10i * u0i)) * i11;
    double u1i = (Hi[1][j] - (L10r * u0i + L10i * u0r)) * i11;
    double u2r = (Hr[2][j] - (L20r * u0r - L20i * u0i) - (L21r * u1r - L21i * u1i)) * i22;
    double u2i = (Hi[2][j] - (L20r * u0i + L20i * u0r) - (L21r * u1i + L21i * u1r)) * i22;
    double u3r = (Hr[3][j] - (L30r * u0r - L30i * u0i) - (L31r * u1r - L31i * u1i)
                           - (L32r * u2r - L32i * u2i)) * i33;
    double u3i = (Hi[3][j] - (L30r * u0i + L30i * u0r) - (L31r * u1i + L31i * u1r)
                           - (L32r * u2i + L32i * u2r)) * i33;
    Hr[0][j] = u0r; Hi[0][j] = u0i; Hr[1][j] = u1r; Hi[1][j] = u1i;
    Hr[2][j] = u2r; Hi[2][j] = u2i; Hr[3][j] = u3r; Hi[3][j] = u3i;
  }
  {
    double v0r = yr[0] * i00,               v0i = yi[0] * i00;
    double v1r = (yr[1] - (L10r * v0r - L10i * v0i)) * i11;
    double v1i = (yi[1] - (L10r * v0i + L10i * v0r)) * i11;
    double v2r = (yr[2] - (L20r * v0r - L20i * v0i) - (L21r * v1r - L21i * v1i)) * i22;
    double v2i = (yi[2] - (L20r * v0i + L20i * v0r) - (L21r * v1i + L21i * v1r)) * i22;
    double v3r = (yr[3] - (L30r * v0r - L30i * v0i) - (L31r * v1r - L31i * v1i)
                        - (L32r * v2r - L32i * v2i)) * i33;
    double v3i = (yi[3] - (L30r * v0i + L30i * v0r) - (L31r * v1i + L31i * v1r)
                        - (L32r * v2i + L32i * v2r)) * i33;
    yr[0] = v0r; yi[0] = v0i; yr[1] = v1r; yi[1] = v1i;
    yr[2] = v2r; yi[2] = v2i; yr[3] = v3r; yi[3] = v3i;
  }

  // fp32 16-QAM table
  const float PRT[16] = { 0.31622776601683794f, 0.31622776601683794f, 0.9486832980505138f, 0.9486832980505138f,
                          0.31622776601683794f, 0.31622776601683794f, 0.9486832980505138f, 0.9486832980505138f,
                         -0.31622776601683794f,-0.31622776601683794f,-0.9486832980505138f,-0.9486832980505138f,
                         -0.31622776601683794f,-0.31622776601683794f,-0.9486832980505138f,-0.9486832980505138f };
  const float PIT[16] = { 0.31622776601683794f, 0.9486832980505138f, 0.31622776601683794f, 0.9486832980505138f,
                         -0.31622776601683794f,-0.9486832980505138f,-0.31622776601683794f,-0.9486832980505138f,
                          0.31622776601683794f, 0.9486832980505138f, 0.31622776601683794f, 0.9486832980505138f,
                         -0.31622776601683794f,-0.9486832980505138f,-0.31622776601683794f,-0.9486832980505138f };

  float llr[4][4];  // [bit k][ue j]
  #pragma unroll
  for (int j = 0; j < 4; ++j) {
    double dj = 0.0, rr = 0.0, ri = 0.0;
    #pragma unroll
    for (int i = 0; i < 4; ++i) {
      dj += Hr[i][j] * Hr[i][j] + Hi[i][j] * Hi[i][j];
      rr += Hr[i][j] * yr[i] + Hi[i][j] * yi[i];
      ri += Hr[i][j] * yi[i] - Hi[i][j] * yr[i];
    }
    float xhr = (float)(rr / dj), xhi = (float)(ri / dj);
    float inoe = (float)(1.0 / fmax(1.0 / dj - 1.0, 1e-12));

    float m0[4] = {-1e30f, -1e30f, -1e30f, -1e30f};
    float m1[4] = {-1e30f, -1e30f, -1e30f, -1e30f};
    #pragma unroll
    for (int p = 0; p < 16; ++p) {
      float dr = xhr - PRT[p], di = xhi - PIT[p];
      float met = -(dr * dr + di * di) * inoe;
      #pragma unroll
      for (int k = 0; k < 4; ++k) {
        if ((p >> (3 - k)) & 1) m1[k] = fmaxf(m1[k], met);
        else                    m0[k] = fmaxf(m0[k], met);
      }
    }
    #pragma unroll
    for (int k = 0; k < 4; ++k) llr[k][j] = m0[k] - m1[k];
  }

  // store: plane 0 = ue{0,1}, plane 1 = ue{2,3}
  float2* pl0 = (float2*)(Lch3 + (size_t)bt * (NNODES * 4));
  float2* pl1 = pl0 + NNODES;
  #pragma unroll
  for (int k = 0; k < 4; ++k) {
    int node = 4 * s + k;
    pl0[node] = make_float2(llr[k][0], llr[k][1]);
    pl1[node] = make_float2(llr[k][2], llr[k][3]);
  }
}

// ---------------- fused LDS-resident BP decoder, 2 codewords / block --------
__device__ __forceinline__ float tanh_half(float m) {
  // tanh(clip(m*0.5, -9.9, 9.9)) with the reference's 1e-7 magnitude floor
  float mc = fminf(fmaxf(m, -19.8f), 19.8f);
  float e = __expf(mc);
  float t = 1.0f - __fdividef(2.0f, e + 1.0f);
  return (t >= 0.0f) ? fmaxf(t, 1e-7f) : fminf(t, -1e-7f);
}

__device__ __forceinline__ float atanh2c(float P, float t) {
  float r = __fdividef(P, t);
  r = fminf(fmaxf(r, -0.999999f), 0.999999f);
  return __logf(__fdividef(1.0f + r, 1.0f - r));
}

// One block = one codeword PAIR. Sibling trick: v2c_e = L[n] + c2v_sibA +
// c2v_sibB (parity edges point both sibs at the永-zero DUMMY slot), so the
// node-parallel vtot pass and sV array are gone: 3 passes, 3 barriers / iter.
__global__ void __launch_bounds__(256) k_bp(const float* __restrict__ Lch3,
                                            const int* __restrict__ vlist,
                                            const int* __restrict__ coff,
                                            const int* __restrict__ cinfo,
                                            const int* __restrict__ esib,
                                            float* __restrict__ out, int E, int ncw) {
  __shared__ float2 sL[NNODES];
  __shared__ float2 sC[EMAX];
  __shared__ float2 sT[EMAX];
  __shared__ float2 sP[MM];

  int tid = threadIdx.x;
  int pairId = blockIdx.x;  // = bt*2 + plane; codewords 2*pairId, 2*pairId+1

  const float2* src = (const float2*)(Lch3 + (size_t)pairId * (NNODES * 2));
  #pragma unroll
  for (int i = 0; i < 4; ++i) {
    int n = tid + TB * i;
    if (n < NNODES) sL[n] = src[n];
  }
  #pragma unroll
  for (int k = 0; k < 8; ++k)
    sC[tid + TB * k] = make_float2(0.0f, 0.0f);  // includes DUMMY slot

  // ---- register caches (loaded once) ----
  int evn[8], epc[8], esa[8], esb[8]; bool eok[8];
  #pragma unroll
  for (int k = 0; k < 8; ++k) {
    int e = tid + TB * k;
    eok[k] = e < E;
    int info = eok[k] ? cinfo[e] : 0;
    int sib  = eok[k] ? esib[e] : (DUMMY << 16) | DUMMY;
    evn[k] = info & 0xffff;
    epc[k] = info >> 16;
    esa[k] = sib >> 16;
    esb[k] = sib & 0xffff;
  }
  int vs0[2], vs1[2], vs2[2];  // decide pass: info nodes only (deg 3)
  #pragma unroll
  for (int i = 0; i < 2; ++i) {
    int n = tid + TB * i;
    if (n < KK) {
      vs0[i] = vlist[n * MAXVDEG];
      vs1[i] = vlist[n * MAXVDEG + 1];
      vs2[i] = vlist[n * MAXVDEG + 2];
    } else { vs0[i] = vs1[i] = vs2[i] = DUMMY; }
  }
  int beg0 = coff[tid], end0 = coff[tid + 1];
  bool c1ok = (tid + TB) < MM;
  int beg1 = c1ok ? coff[tid + TB] : 0;
  int end1 = c1ok ? coff[tid + TB + 1] : 0;
  __syncthreads();

  for (int it = 0; it < NITERS; ++it) {
    // v2c tanh (edge-parallel, uniform; vtot folded in via siblings)
    #pragma unroll
    for (int k = 0; k < 8; ++k) {
      if (eok[k]) {
        int e = tid + TB * k;
        float2 L = sL[evn[k]];
        float2 ca = sC[esa[k]], cb = sC[esb[k]];
        sT[e] = make_float2(tanh_half(L.x + ca.x + cb.x),
                            tanh_half(L.y + ca.y + cb.y));
      }
    }
    __syncthreads();
    // per-check products (multiplies only under divergence)
    {
      float px = 1.0f, py = 1.0f;
      for (int e = beg0; e < end0; ++e) { float2 tt = sT[e]; px *= tt.x; py *= tt.y; }
      sP[tid] = make_float2(px, py);
      if (c1ok) {
        float qx = 1.0f, qy = 1.0f;
        for (int e = beg1; e < end1; ++e) { float2 tt = sT[e]; qx *= tt.x; qy *= tt.y; }
        sP[tid + TB] = make_float2(qx, qy);
      }
    }
    __syncthreads();
    // c2v update (edge-parallel, uniform; all transcendentals here)
    #pragma unroll
    for (int k = 0; k < 8; ++k) {
      if (eok[k]) {
        int e = tid + TB * k;
        float2 P = sP[epc[k]];
        float2 tt = sT[e];
        sC[e] = make_float2(atanh2c(P.x, tt.x), atanh2c(P.y, tt.y));
      }
    }
    __syncthreads();
  }

  // decide info bits for both codewords
  int cw0 = pairId * 2;
  float* o0 = out + (size_t)ncw * KK + (size_t)cw0 * KK;
  float* o1 = o0 + KK;
  #pragma unroll
  for (int i = 0; i < 2; ++i) {
    int n = tid + TB * i;
    if (n < KK) {
      float2 a = sL[n];
      float2 c0 = sC[vs0[i]], c1 = sC[vs1[i]], c2 = sC[vs2[i]];
      float ax = a.x + c0.x + c1.x + c2.x;
      float ay = a.y + c0.y + c1.y + c2.y;
      o0[n] = (ax < 0.0f) ? 1.0f : 0.0f;
      o1[n] = (ay < 0.0f) ? 1.0f : 0.0f;
    }
  }
}

// ---------------- launcher ----------------
extern "C" void kernel_launch(void* const* d_in, const int* in_sizes, int n_in,
                              void* d_out, int out_size, void* d_ws, size_t ws_size,
                              hipStream_t stream) {
  const float* ebno = (const float*)d_in[1];
  const int*   b    = (const int*)d_in[2];
  const int*   P    = (const int*)d_in[3];
  const int*   cn   = (const int*)d_in[4];
  const int*   vn   = (const int*)d_in[5];
  const float* h_re = (const float*)d_in[6];
  const float* h_im = (const float*)d_in[7];
  const float* nre  = (const float*)d_in[8];
  const float* nim  = (const float*)d_in[9];
  float* out = (float*)d_out;

  int E     = in_sizes[4];
  int batch = in_sizes[2] / (4 * KK);
  int ncw   = batch * 4;
  int T     = batch * NSYM;

  char* ws = (char*)d_ws;
  size_t off = 0;
  auto alloc = [&](size_t bytes) -> void* {
    void* p = ws + off;
    off += (bytes + 255) & ~(size_t)255;
    return p;
  };
  float*    Lch3   = (float*)alloc((size_t)NNODES * ncw * 4);
  int*      symidx = (int*)alloc((size_t)ncw * NSYM * 4);
  unsigned* Ppack  = (unsigned*)alloc((size_t)MM * 16 * 4);
  unsigned* bpack  = (unsigned*)alloc((size_t)ncw * 16 * 4);
  int*      cdeg   = (int*)alloc((size_t)MM * 4);
  int*      coff   = (int*)alloc((size_t)(MM + 1) * 4);
  int*      cur    = (int*)alloc((size_t)MM * 4);
  int*      cinfo  = (int*)alloc((size_t)EMAX * 4);
  int*      vdeg   = (int*)alloc((size_t)NNODES * 4);
  int*      vlist  = (int*)alloc((size_t)NNODES * MAXVDEG * 4);
  int*      esib   = (int*)alloc((size_t)EMAX * 4);
  double*   nobuf  = (double*)alloc(2 * 8);
  (void)ws_size; (void)n_in; (void)out_size;

  const int tb = 256;
  hipMemsetAsync(cdeg, 0, (size_t)MM * 4, stream);
  hipMemsetAsync(vdeg, 0, (size_t)NNODES * 4, stream);

  k_no<<<dim3(1), dim3(1), 0, stream>>>(ebno, nobuf);
  k_pack_P<<<dim3((MM * 16 + tb - 1) / tb), dim3(tb), 0, stream>>>(P, Ppack);
  k_pack_b<<<dim3((ncw * 16 + tb - 1) / tb), dim3(tb), 0, stream>>>(b, bpack, ncw);
  k_sym<<<dim3((ncw * NSYM + tb - 1) / tb), dim3(tb), 0, stream>>>(bpack, Ppack, symidx, ncw);
  k_bf<<<dim3((ncw * KK + tb - 1) / tb), dim3(tb), 0, stream>>>(b, out, ncw * KK);

  k_count<<<dim3((E + tb - 1) / tb), dim3(tb), 0, stream>>>(cn, E, cdeg);
  k_scan<<<dim3(1), dim3(512), 0, stream>>>(cdeg, coff, cur);
  k_fill2<<<dim3((E + tb - 1) / tb), dim3(tb), 0, stream>>>(cn, vn, E, cur, cinfo, vdeg, vlist);
  k_sib<<<dim3((E + tb - 1) / tb), dim3(tb), 0, stream>>>(cinfo, vdeg, vlist, E, esib);

  k_lmmse<<<dim3((T + tb - 1) / tb), dim3(tb), 0, stream>>>(h_re, h_im, nre, nim, nobuf, symidx, Lch3, T, ncw);

  k_bp<<<dim3(ncw / 2), dim3(tb), 0, stream>>>(Lch3, vlist, coff, cinfo, esib, out, E, ncw);
}

// Round 8
// 230.207 us; speedup vs baseline: 1.1651x; 1.1651x over previous
//
#include <hip/hip_runtime.h>
#include <math.h>

// Problem constants (from reference)
#define KK     500   // info bits
#define MM     500   // parity checks
#define NNODES 1000  // N = K + M variable nodes
#define NSYM   250   // N / BPS
#define NITERS 5
#define MAXVDEG 4    // info vars degree exactly 3 (row weight of P), parity vars 1
#define EMAX   2048  // E = 2000 edges
#define TB     256

// ---------------- bit packing ----------------
__global__ void __launch_bounds__(256) k_pack_P(const int* __restrict__ P, unsigned* __restrict__ Ppack) {
  int id = blockIdx.x * blockDim.x + threadIdx.x;
  if (id >= MM * 16) return;
  int j = id >> 4, w = id & 15;
  unsigned word = 0u;
  int base = w * 32;
  for (int bit = 0; bit < 32; ++bit) {
    int i = base + bit;
    if (i < KK && P[i * MM + j] != 0) word |= (1u << bit);
  }
  Ppack[j * 16 + w] = word;
}

__global__ void __launch_bounds__(256) k_pack_b(const int* __restrict__ b, unsigned* __restrict__ bpack, int ncw) {
  int id = blockIdx.x * blockDim.x + threadIdx.x;
  if (id >= ncw * 16) return;
  int cw = id >> 4, w = id & 15;
  unsigned word = 0u;
  int base = w * 32;
  for (int bit = 0; bit < 32; ++bit) {
    int i = base + bit;
    if (i < KK && b[cw * KK + i] != 0) word |= (1u << bit);
  }
  bpack[cw * 16 + w] = word;
}

// ---------------- symbol indices, layout [bt][s][ue] ----------------
__global__ void __launch_bounds__(256) k_sym(const unsigned* __restrict__ bpack, const unsigned* __restrict__ Ppack,
                                             int* __restrict__ symidx2, int ncw) {
  int id = blockIdx.x * blockDim.x + threadIdx.x;
  if (id >= ncw * NSYM) return;
  int cw = id / NSYM, s = id - cw * NSYM;
  int idx = 0;
  #pragma unroll
  for (int k = 0; k < 4; ++k) {
    int n = 4 * s + k;
    int bit;
    if (n < KK) {
      bit = (bpack[cw * 16 + (n >> 5)] >> (n & 31)) & 1;
    } else {
      int j = n - KK;
      int cnt = 0;
      #pragma unroll
      for (int w = 0; w < 16; ++w) cnt += __popc(bpack[cw * 16 + w] & Ppack[j * 16 + w]);
      bit = cnt & 1;
    }
    idx = (idx << 1) | bit;  // MSB-first: weights 8,4,2,1
  }
  symidx2[(((cw >> 2) * NSYM) + s) * 4 + (cw & 3)] = idx;
}

// ---------------- output 0: bf = float(b) ----------------
__global__ void __launch_bounds__(256) k_bf(const int* __restrict__ b, float* __restrict__ out, int n) {
  int id = blockIdx.x * blockDim.x + threadIdx.x;
  if (id < n) out[id] = (float)b[id];
}

// ---------------- noise variance (once, not 250k fp64 pow calls) ----------
__global__ void k_no(const float* __restrict__ ebno, double* __restrict__ nobuf) {
  double no = 1.0 / (pow(10.0, (double)ebno[0] * 0.1) * 2.0);  // BPS*RATE = 2
  nobuf[0] = no;
  nobuf[1] = sqrt(no * 0.5);
}

// ---------------- graph build: count -> scan -> fill ----------------------
__global__ void __launch_bounds__(256) k_count(const int* __restrict__ cn, int E, int* __restrict__ cdeg) {
  int e = blockIdx.x * blockDim.x + threadIdx.x;
  if (e < E) atomicAdd(&cdeg[cn[e]], 1);
}

__global__ void __launch_bounds__(512) k_scan(const int* __restrict__ cdeg,
                                              int* __restrict__ coff, int* __restrict__ cur) {
  __shared__ int s[512];
  int tid = threadIdx.x;
  int v = (tid < MM) ? cdeg[tid] : 0;
  s[tid] = v;
  __syncthreads();
  for (int o = 1; o < 512; o <<= 1) {
    int x = (tid >= o) ? s[tid - o] : 0;
    __syncthreads();
    s[tid] += x;
    __syncthreads();
  }
  if (tid < MM) {
    int excl = s[tid] - v;
    coff[tid] = excl;
    cur[tid]  = excl;
    if (tid == MM - 1) coff[MM] = s[tid];
  }
}

__global__ void __launch_bounds__(256) k_fill2(const int* __restrict__ cn, const int* __restrict__ vn, int E,
                                               int* __restrict__ cur, int* __restrict__ cinfo,
                                               int* __restrict__ vdeg, int* __restrict__ vlist) {
  int e = blockIdx.x * blockDim.x + threadIdx.x;
  if (e >= E) return;
  int c = cn[e], n = vn[e];
  int slot = atomicAdd(&cur[c], 1);
  cinfo[slot] = (c << 16) | n;
  int t = atomicAdd(&vdeg[n], 1);
  if (t < MAXVDEG) vlist[n * MAXVDEG + t] = slot;
}

// ---------------- 16-QAM constellation (fp64 for TX symbol) ----------------
__device__ __forceinline__ void qam_point(int p, double& re, double& im) {
  const double s = 0.31622776601683794;  // 1/sqrt(10)
  int b0 = (p >> 3) & 1, b1 = (p >> 2) & 1, b2 = (p >> 1) & 1, b3 = p & 1;
  re = (double)((1 - 2 * b0) * (2 - (1 - 2 * b2))) * s;
  im = (double)((1 - 2 * b1) * (2 - (1 - 2 * b3))) * s;
}

// ---------------- channel + LMMSE + max-log LLR --------------------------
// fp64 channel/Cholesky/solve (scalarized lower-triangular L); fp32 demap.
// Output Lch3[bt][pair][node][2]: contiguous float2 per codeword-pair.
__global__ void __launch_bounds__(256, 1)
k_lmmse(const float* __restrict__ h_re, const float* __restrict__ h_im,
        const float* __restrict__ n_re, const float* __restrict__ n_im,
        const double* __restrict__ nobuf, const int* __restrict__ symidx2,
        float* __restrict__ Lch3, int T, int ncw) {
  int t = blockIdx.x * blockDim.x + threadIdx.x;
  if (t >= T) return;
  int bt = t / NSYM, s = t - bt * NSYM;

  double no = nobuf[0];
  double sq = nobuf[1];
  const double is2 = 0.7071067811865475244;  // 1/sqrt(2)

  double Hr[4][4], Hi[4][4];
  {
    const float4* hr4 = (const float4*)h_re;
    const float4* hi4 = (const float4*)h_im;
    #pragma unroll
    for (int i = 0; i < 4; ++i) {
      float4 a = hr4[t * 4 + i], c = hi4[t * 4 + i];
      Hr[i][0] = (double)a.x * is2; Hr[i][1] = (double)a.y * is2;
      Hr[i][2] = (double)a.z * is2; Hr[i][3] = (double)a.w * is2;
      Hi[i][0] = (double)c.x * is2; Hi[i][1] = (double)c.y * is2;
      Hi[i][2] = (double)c.z * is2; Hi[i][3] = (double)c.w * is2;
    }
  }

  double xr[4], xi[4];
  {
    int4 ss = ((const int4*)symidx2)[bt * NSYM + s];
    qam_point(ss.x, xr[0], xi[0]);
    qam_point(ss.y, xr[1], xi[1]);
    qam_point(ss.z, xr[2], xi[2]);
    qam_point(ss.w, xr[3], xi[3]);
  }

  // y = H x + w
  double yr[4], yi[4];
  {
    float4 wr = ((const float4*)n_re)[t];
    float4 wi = ((const float4*)n_im)[t];
    float wrv[4] = {wr.x, wr.y, wr.z, wr.w};
    float wiv[4] = {wi.x, wi.y, wi.z, wi.w};
    #pragma unroll
    for (int i = 0; i < 4; ++i) {
      double ar = (double)wrv[i] * sq;
      double ai = (double)wiv[i] * sq;
      #pragma unroll
      for (int j = 0; j < 4; ++j) {
        ar += Hr[i][j] * xr[j] - Hi[i][j] * xi[j];
        ai += Hr[i][j] * xi[j] + Hi[i][j] * xr[j];
      }
      yr[i] = ar; yi[i] = ai;
    }
  }

  // A = H H^H + no I, lower triangle, into scalars
  auto dotc = [&](int i, int j, double& ar, double& ai) {
    double r = 0.0, m = 0.0;
    #pragma unroll
    for (int k = 0; k < 4; ++k) {
      r += Hr[i][k] * Hr[j][k] + Hi[i][k] * Hi[j][k];
      m += Hi[i][k] * Hr[j][k] - Hr[i][k] * Hi[j][k];
    }
    ar = r; ai = m;
  };
  double a00, a11, a22, a33, dum;
  double a10r, a10i, a20r, a20i, a21r, a21i, a30r, a30i, a31r, a31i, a32r, a32i;
  dotc(0, 0, a00, dum);  a00 += no;
  dotc(1, 0, a10r, a10i);
  dotc(1, 1, a11, dum);  a11 += no;
  dotc(2, 0, a20r, a20i);
  dotc(2, 1, a21r, a21i);
  dotc(2, 2, a22, dum);  a22 += no;
  dotc(3, 0, a30r, a30i);
  dotc(3, 1, a31r, a31i);
  dotc(3, 2, a32r, a32i);
  dotc(3, 3, a33, dum);  a33 += no;

  // Cholesky A = L L^H (scalarized)
  double L00 = sqrt(a00);
  double i00 = 1.0 / L00;
  double L10r = a10r * i00, L10i = a10i * i00;
  double L20r = a20r * i00, L20i = a20i * i00;
  double L30r = a30r * i00, L30i = a30i * i00;
  double L11 = sqrt(a11 - (L10r * L10r + L10i * L10i));
  double i11 = 1.0 / L11;
  double L21r = (a21r - (L20r * L10r + L20i * L10i)) * i11;
  double L21i = (a21i - (L20i * L10r - L20r * L10i)) * i11;
  double L31r = (a31r - (L30r * L10r + L30i * L10i)) * i11;
  double L31i = (a31i - (L30i * L10r - L30r * L10i)) * i11;
  double L22 = sqrt(a22 - (L20r * L20r + L20i * L20i) - (L21r * L21r + L21i * L21i));
  double i22 = 1.0 / L22;
  double L32r = (a32r - (L30r * L20r + L30i * L20i) - (L31r * L21r + L31i * L21i)) * i22;
  double L32i = (a32i - (L30i * L20r - L30r * L20i) - (L31i * L21r - L31r * L21i)) * i22;
  double L33 = sqrt(a33 - (L30r * L30r + L30i * L30i) - (L31r * L31r + L31i * L31i)
                        - (L32r * L32r + L32i * L32i));
  double i33 = 1.0 / L33;

  // forward solve: U = L^{-1} H (in place on H), v = L^{-1} y (in place on y)
  #pragma unroll
  for (int j = 0; j < 4; ++j) {
    double u0r = Hr[0][j] * i00,               u0i = Hi[0][j] * i00;
    double u1r = (Hr[1][j] - (L10r * u0r - L10i * u0i)) * i11;
    double u1i = (Hi[1][j] - (L10r * u0i + L10i * u0r)) * i11;
    double u2r = (Hr[2][j] - (L20r * u0r - L20i * u0i) - (L21r * u1r - L21i * u1i)) * i22;
    double u2i = (Hi[2][j] - (L20r * u0i + L20i * u0r) - (L21r * u1i + L21i * u1r)) * i22;
    double u3r = (Hr[3][j] - (L30r * u0r - L30i * u0i) - (L31r * u1r - L31i * u1i)
                           - (L32r * u2r - L32i * u2i)) * i33;
    double u3i = (Hi[3][j] - (L30r * u0i + L30i * u0r) - (L31r * u1i + L31i * u1r)
                           - (L32r * u2i + L32i * u2r)) * i33;
    Hr[0][j] = u0r; Hi[0][j] = u0i; Hr[1][j] = u1r; Hi[1][j] = u1i;
    Hr[2][j] = u2r; Hi[2][j] = u2i; Hr[3][j] = u3r; Hi[3][j] = u3i;
  }
  {
    double v0r = yr[0] * i00,               v0i = yi[0] * i00;
    double v1r = (yr[1] - (L10r * v0r - L10i * v0i)) * i11;
    double v1i = (yi[1] - (L10r * v0i + L10i * v0r)) * i11;
    double v2r = (yr[2] - (L20r * v0r - L20i * v0i) - (L21r * v1r - L21i * v1i)) * i22;
    double v2i = (yi[2] - (L20r * v0i + L20i * v0r) - (L21r * v1i + L21i * v1r)) * i22;
    double v3r = (yr[3] - (L30r * v0r - L30i * v0i) - (L31r * v1r - L31i * v1i)
                        - (L32r * v2r - L32i * v2i)) * i33;
    double v3i = (yi[3] - (L30r * v0i + L30i * v0r) - (L31r * v1i + L31i * v1r)
                        - (L32r * v2i + L32i * v2r)) * i33;
    yr[0] = v0r; yi[0] = v0i; yr[1] = v1r; yi[1] = v1i;
    yr[2] = v2r; yi[2] = v2i; yr[3] = v3r; yi[3] = v3i;
  }

  // fp32 16-QAM table
  const float PRT[16] = { 0.31622776601683794f, 0.31622776601683794f, 0.9486832980505138f, 0.9486832980505138f,
                          0.31622776601683794f, 0.31622776601683794f, 0.9486832980505138f, 0.9486832980505138f,
                         -0.31622776601683794f,-0.31622776601683794f,-0.9486832980505138f,-0.9486832980505138f,
                         -0.31622776601683794f,-0.31622776601683794f,-0.9486832980505138f,-0.9486832980505138f };
  const float PIT[16] = { 0.31622776601683794f, 0.9486832980505138f, 0.31622776601683794f, 0.9486832980505138f,
                         -0.31622776601683794f,-0.9486832980505138f,-0.31622776601683794f,-0.9486832980505138f,
                          0.31622776601683794f, 0.9486832980505138f, 0.31622776601683794f, 0.9486832980505138f,
                         -0.31622776601683794f,-0.9486832980505138f,-0.31622776601683794f,-0.9486832980505138f };

  float llr[4][4];  // [bit k][ue j]
  #pragma unroll
  for (int j = 0; j < 4; ++j) {
    double dj = 0.0, rr = 0.0, ri = 0.0;
    #pragma unroll
    for (int i = 0; i < 4; ++i) {
      dj += Hr[i][j] * Hr[i][j] + Hi[i][j] * Hi[i][j];
      rr += Hr[i][j] * yr[i] + Hi[i][j] * yi[i];
      ri += Hr[i][j] * yi[i] - Hi[i][j] * yr[i];
    }
    float xhr = (float)(rr / dj), xhi = (float)(ri / dj);
    float inoe = (float)(1.0 / fmax(1.0 / dj - 1.0, 1e-12));

    float m0[4] = {-1e30f, -1e30f, -1e30f, -1e30f};
    float m1[4] = {-1e30f, -1e30f, -1e30f, -1e30f};
    #pragma unroll
    for (int p = 0; p < 16; ++p) {
      float dr = xhr - PRT[p], di = xhi - PIT[p];
      float met = -(dr * dr + di * di) * inoe;
      #pragma unroll
      for (int k = 0; k < 4; ++k) {
        if ((p >> (3 - k)) & 1) m1[k] = fmaxf(m1[k], met);
        else                    m0[k] = fmaxf(m0[k], met);
      }
    }
    #pragma unroll
    for (int k = 0; k < 4; ++k) llr[k][j] = m0[k] - m1[k];
  }

  // store: plane 0 = ue{0,1}, plane 1 = ue{2,3}
  float2* pl0 = (float2*)(Lch3 + (size_t)bt * (NNODES * 4));
  float2* pl1 = pl0 + NNODES;
  #pragma unroll
  for (int k = 0; k < 4; ++k) {
    int node = 4 * s + k;
    pl0[node] = make_float2(llr[k][0], llr[k][1]);
    pl1[node] = make_float2(llr[k][2], llr[k][3]);
  }
}

// ---------------- fused LDS-resident BP decoder, 2 codewords / block --------
__device__ __forceinline__ float tanh_half(float m) {
  // tanh(clip(m*0.5, -9.9, 9.9)) with the reference's 1e-7 magnitude floor
  float mc = fminf(fmaxf(m, -19.8f), 19.8f);
  float e = __expf(mc);
  float t = 1.0f - __fdividef(2.0f, e + 1.0f);
  return (t >= 0.0f) ? fmaxf(t, 1e-7f) : fminf(t, -1e-7f);
}

__device__ __forceinline__ float atanh2c(float P, float t) {
  float r = __fdividef(P, t);
  r = fminf(fmaxf(r, -0.999999f), 0.999999f);
  return __logf(__fdividef(1.0f + r, 1.0f - r));
}
__device__ __forceinline__ float2 atanh2v(float2 P, float2 t) {
  return make_float2(atanh2c(P.x, t.x), atanh2c(P.y, t.y));
}

// One block = one codeword PAIR (same Tanner graph).
// c2v is never stored: it is reconstructed as atanh2(P_c / t_e) from the
// per-check product sP and per-edge tanh sT.  Parity nodes (degree 1) have
// v2c == L, so their sT is constant: computed once in the preamble; the
// iteration's var pass touches only the 500 info nodes (1500 edges).
// 2 passes + 2 barriers per iteration; LDS = sL+sT+sP ~ 28.5 KB -> 5 blk/CU.
__global__ void __launch_bounds__(256) k_bp(const float* __restrict__ Lch3,
                                            const int* __restrict__ vlist,
                                            const int* __restrict__ coff,
                                            const int* __restrict__ cinfo,
                                            float* __restrict__ out, int E, int ncw) {
  __shared__ float2 sL[NNODES];   // channel LLRs
  __shared__ float2 sT[EMAX];     // tanh(v2c/2) per edge slot
  __shared__ float2 sP[512];      // per-check product of tanh

  int tid = threadIdx.x;
  int pairId = blockIdx.x;  // = bt*2 + plane; codewords 2*pairId, 2*pairId+1

  const float2* src = (const float2*)(Lch3 + (size_t)pairId * (NNODES * 2));
  #pragma unroll
  for (int i = 0; i < 4; ++i) {
    int n = tid + TB * i;
    if (n < NNODES) sL[n] = src[n];
  }

  // parity-node constant tanh (from global src; no barrier dependency on sL)
  #pragma unroll
  for (int i = 0; i < 2; ++i) {
    int n = KK + tid + TB * i;
    if (n < NNODES) {
      int slot = vlist[n * MAXVDEG];
      float2 L = src[n];
      sT[slot] = make_float2(tanh_half(L.x), tanh_half(L.y));
    }
  }

  // register cache: per info node, 3 packed (check<<16)|slot
  int pk0[2], pk1[2], pk2[2]; bool iok[2];
  #pragma unroll
  for (int i = 0; i < 2; ++i) {
    int n = tid + TB * i;
    iok[i] = n < KK;
    pk0[i] = pk1[i] = pk2[i] = 0;
    if (iok[i]) {
      int s0 = vlist[n * MAXVDEG], s1 = vlist[n * MAXVDEG + 1], s2 = vlist[n * MAXVDEG + 2];
      pk0[i] = (cinfo[s0] & 0xffff0000) | s0;
      pk1[i] = (cinfo[s1] & 0xffff0000) | s1;
      pk2[i] = (cinfo[s2] & 0xffff0000) | s2;
    }
  }
  int beg0 = coff[tid], end0 = coff[tid + 1];
  bool c1ok = (tid + TB) < MM;
  int beg1 = c1ok ? coff[tid + TB] : 0;
  int end1 = c1ok ? coff[tid + TB + 1] : 0;
  __syncthreads();

  for (int it = 0; it < NITERS; ++it) {
    // ---- pass 1: info-node var update (c2v reconstructed from sP/sT) ----
    if (it == 0) {
      // c2v == 0 -> v2c = L for every edge of the node: one tanh, 3 stores
      #pragma unroll
      for (int i = 0; i < 2; ++i) {
        if (iok[i]) {
          int n = tid + TB * i;
          float2 L = sL[n];
          float2 t = make_float2(tanh_half(L.x), tanh_half(L.y));
          sT[pk0[i] & 0xffff] = t;
          sT[pk1[i] & 0xffff] = t;
          sT[pk2[i] & 0xffff] = t;
        }
      }
    } else {
      #pragma unroll
      for (int i = 0; i < 2; ++i) {
        if (iok[i]) {
          int n = tid + TB * i;
          int s0 = pk0[i] & 0xffff, c0 = ((unsigned)pk0[i]) >> 16;
          int s1 = pk1[i] & 0xffff, c1 = ((unsigned)pk1[i]) >> 16;
          int s2 = pk2[i] & 0xffff, c2 = ((unsigned)pk2[i]) >> 16;
          float2 g0 = atanh2v(sP[c0], sT[s0]);
          float2 g1 = atanh2v(sP[c1], sT[s1]);
          float2 g2 = atanh2v(sP[c2], sT[s2]);
          float2 L = sL[n];
          float vx = L.x + g0.x + g1.x + g2.x;
          float vy = L.y + g0.y + g1.y + g2.y;
          sT[s0] = make_float2(tanh_half(vx - g0.x), tanh_half(vy - g0.y));
          sT[s1] = make_float2(tanh_half(vx - g1.x), tanh_half(vy - g1.y));
          sT[s2] = make_float2(tanh_half(vx - g2.x), tanh_half(vy - g2.y));
        }
      }
    }
    __syncthreads();
    // ---- pass 2: per-check products ----
    {
      float px = 1.0f, py = 1.0f;
      for (int e = beg0; e < end0; ++e) { float2 tt = sT[e]; px *= tt.x; py *= tt.y; }
      sP[tid] = make_float2(px, py);
      if (c1ok) {
        float qx = 1.0f, qy = 1.0f;
        for (int e = beg1; e < end1; ++e) { float2 tt = sT[e]; qx *= tt.x; qy *= tt.y; }
        sP[tid + TB] = make_float2(qx, qy);
      }
    }
    __syncthreads();
  }

  // ---- decide: reconstruct final c2v, threshold ----
  int cw0 = pairId * 2;
  float* o0 = out + (size_t)ncw * KK + (size_t)cw0 * KK;
  float* o1 = o0 + KK;
  #pragma unroll
  for (int i = 0; i < 2; ++i) {
    if (iok[i]) {
      int n = tid + TB * i;
      int s0 = pk0[i] & 0xffff, c0 = ((unsigned)pk0[i]) >> 16;
      int s1 = pk1[i] & 0xffff, c1 = ((unsigned)pk1[i]) >> 16;
      int s2 = pk2[i] & 0xffff, c2 = ((unsigned)pk2[i]) >> 16;
      float2 g0 = atanh2v(sP[c0], sT[s0]);
      float2 g1 = atanh2v(sP[c1], sT[s1]);
      float2 g2 = atanh2v(sP[c2], sT[s2]);
      float2 L = sL[n];
      float ax = L.x + g0.x + g1.x + g2.x;
      float ay = L.y + g0.y + g1.y + g2.y;
      o0[n] = (ax < 0.0f) ? 1.0f : 0.0f;
      o1[n] = (ay < 0.0f) ? 1.0f : 0.0f;
    }
  }
}

// ---------------- launcher ----------------
extern "C" void kernel_launch(void* const* d_in, const int* in_sizes, int n_in,
                              void* d_out, int out_size, void* d_ws, size_t ws_size,
                              hipStream_t stream) {
  const float* ebno = (const float*)d_in[1];
  const int*   b    = (const int*)d_in[2];
  const int*   P    = (const int*)d_in[3];
  const int*   cn   = (const int*)d_in[4];
  const int*   vn   = (const int*)d_in[5];
  const float* h_re = (const float*)d_in[6];
  const float* h_im = (const float*)d_in[7];
  const float* nre  = (const float*)d_in[8];
  const float* nim  = (const float*)d_in[9];
  float* out = (float*)d_out;

  int E     = in_sizes[4];
  int batch = in_sizes[2] / (4 * KK);
  int ncw   = batch * 4;
  int T     = batch * NSYM;

  char* ws = (char*)d_ws;
  size_t off = 0;
  auto alloc = [&](size_t bytes) -> void* {
    void* p = ws + off;
    off += (bytes + 255) & ~(size_t)255;
    return p;
  };
  float*    Lch3   = (float*)alloc((size_t)NNODES * ncw * 4);
  int*      symidx = (int*)alloc((size_t)ncw * NSYM * 4);
  unsigned* Ppack  = (unsigned*)alloc((size_t)MM * 16 * 4);
  unsigned* bpack  = (unsigned*)alloc((size_t)ncw * 16 * 4);
  int*      cdeg   = (int*)alloc((size_t)MM * 4);
  int*      coff   = (int*)alloc((size_t)(MM + 1) * 4);
  int*      cur    = (int*)alloc((size_t)MM * 4);
  int*      cinfo  = (int*)alloc((size_t)EMAX * 4);
  int*      vdeg   = (int*)alloc((size_t)NNODES * 4);
  int*      vlist  = (int*)alloc((size_t)NNODES * MAXVDEG * 4);
  double*   nobuf  = (double*)alloc(2 * 8);
  (void)ws_size; (void)n_in; (void)out_size;

  const int tb = 256;
  hipMemsetAsync(cdeg, 0, (size_t)MM * 4, stream);
  hipMemsetAsync(vdeg, 0, (size_t)NNODES * 4, stream);

  k_no<<<dim3(1), dim3(1), 0, stream>>>(ebno, nobuf);
  k_pack_P<<<dim3((MM * 16 + tb - 1) / tb), dim3(tb), 0, stream>>>(P, Ppack);
  k_pack_b<<<dim3((ncw * 16 + tb - 1) / tb), dim3(tb), 0, stream>>>(b, bpack, ncw);
  k_sym<<<dim3((ncw * NSYM + tb - 1) / tb), dim3(tb), 0, stream>>>(bpack, Ppack, symidx, ncw);
  k_bf<<<dim3((ncw * KK + tb - 1) / tb), dim3(tb), 0, stream>>>(b, out, ncw * KK);

  k_count<<<dim3((E + tb - 1) / tb), dim3(tb), 0, stream>>>(cn, E, cdeg);
  k_scan<<<dim3(1), dim3(512), 0, stream>>>(cdeg, coff, cur);
  k_fill2<<<dim3((E + tb - 1) / tb), dim3(tb), 0, stream>>>(cn, vn, E, cur, cinfo, vdeg, vlist);

  k_lmmse<<<dim3((T + tb - 1) / tb), dim3(tb), 0, stream>>>(h_re, h_im, nre, nim, nobuf, symidx, Lch3, T, ncw);

  k_bp<<<dim3(ncw / 2), dim3(tb), 0, stream>>>(Lch3, vlist, coff, cinfo, out, E, ncw);
}

// Round 9
// 212.224 us; speedup vs baseline: 1.2639x; 1.0847x over previous
//
#include <hip/hip_runtime.h>
#include <math.h>

// Problem constants (from reference)
#define KK     500   // info bits
#define MM     500   // parity checks
#define NNODES 1000  // N = K + M variable nodes
#define NSYM   250   // N / BPS
#define NITERS 5
#define MAXVDEG 4    // info vars degree exactly 3 (row weight of P), parity vars 1
#define EMAX   2048  // E = 2000 edges
#define TB     256

// ---------------- merged bit packing (P columns + codeword bits) -----------
__global__ void __launch_bounds__(256) k_pack(const int* __restrict__ P, const int* __restrict__ b,
                                              unsigned* __restrict__ Ppack, unsigned* __restrict__ bpack,
                                              int ncw) {
  int id = blockIdx.x * blockDim.x + threadIdx.x;
  if (id < MM * 16) {
    int j = id >> 4, w = id & 15;
    unsigned word = 0u;
    int base = w * 32;
    for (int bit = 0; bit < 32; ++bit) {
      int i = base + bit;
      if (i < KK && P[i * MM + j] != 0) word |= (1u << bit);
    }
    Ppack[j * 16 + w] = word;
  } else {
    int id2 = id - MM * 16;
    if (id2 >= ncw * 16) return;
    int cw = id2 >> 4, w = id2 & 15;
    unsigned word = 0u;
    int base = w * 32;
    for (int bit = 0; bit < 32; ++bit) {
      int i = base + bit;
      if (i < KK && b[cw * KK + i] != 0) word |= (1u << bit);
    }
    bpack[cw * 16 + w] = word;
  }
}

// ---------------- merged: bf output + symbol indices ----------------------
__global__ void __launch_bounds__(256) k_symbf(const unsigned* __restrict__ bpack,
                                               const unsigned* __restrict__ Ppack,
                                               const int* __restrict__ b,
                                               float* __restrict__ out,
                                               int* __restrict__ symidx2, int ncw) {
  int id = blockIdx.x * blockDim.x + threadIdx.x;
  int nbf = ncw * KK;
  if (id < nbf) {
    out[id] = (float)b[id];
    return;
  }
  int id2 = id - nbf;
  if (id2 >= ncw * NSYM) return;
  int cw = id2 / NSYM, s = id2 - cw * NSYM;
  int idx = 0;
  #pragma unroll
  for (int k = 0; k < 4; ++k) {
    int n = 4 * s + k;
    int bit;
    if (n < KK) {
      bit = (bpack[cw * 16 + (n >> 5)] >> (n & 31)) & 1;
    } else {
      int j = n - KK;
      int cnt = 0;
      #pragma unroll
      for (int w = 0; w < 16; ++w) cnt += __popc(bpack[cw * 16 + w] & Ppack[j * 16 + w]);
      bit = cnt & 1;
    }
    idx = (idx << 1) | bit;  // MSB-first: weights 8,4,2,1
  }
  symidx2[(((cw >> 2) * NSYM) + s) * 4 + (cw & 3)] = idx;
}

// ---------------- fused graph build + noise scalar (single block) ----------
// count -> LDS scan -> fill (compact check-CSR + var adjacency in slot ids)
__global__ void __launch_bounds__(512) k_graph(const int* __restrict__ cn, const int* __restrict__ vn,
                                               int E, const float* __restrict__ ebno,
                                               int* __restrict__ cinfo, int* __restrict__ vlist,
                                               int* __restrict__ coff, double* __restrict__ nobuf) {
  __shared__ int sdeg[512];
  __shared__ int ssc[512];
  __shared__ int scur[512];
  __shared__ int svc[NNODES];
  int tid = threadIdx.x;
  sdeg[tid] = 0;
  for (int n = tid; n < NNODES; n += 512) svc[n] = 0;
  __syncthreads();
  for (int e = tid; e < E; e += 512) atomicAdd(&sdeg[cn[e]], 1);
  __syncthreads();
  int v = sdeg[tid];
  ssc[tid] = v;
  __syncthreads();
  for (int o = 1; o < 512; o <<= 1) {
    int x = (tid >= o) ? ssc[tid - o] : 0;
    __syncthreads();
    ssc[tid] += x;
    __syncthreads();
  }
  int excl = ssc[tid] - v;
  scur[tid] = excl;
  if (tid < MM) {
    coff[tid] = excl;
    if (tid == MM - 1) coff[MM] = ssc[tid];
  }
  __syncthreads();
  for (int e = tid; e < E; e += 512) {
    int c = cn[e], n = vn[e];
    int slot = atomicAdd(&scur[c], 1);
    cinfo[slot] = (c << 16) | n;
    int t = atomicAdd(&svc[n], 1);
    if (t < MAXVDEG) vlist[n * MAXVDEG + t] = slot;
  }
  if (tid == 0) {
    double no = 1.0 / (pow(10.0, (double)ebno[0] * 0.1) * 2.0);  // BPS*RATE = 2
    nobuf[0] = no;
    nobuf[1] = sqrt(no * 0.5);
  }
}

// ---------------- 16-QAM constellation (fp64 for TX symbol) ----------------
__device__ __forceinline__ void qam_point(int p, double& re, double& im) {
  const double s = 0.31622776601683794;  // 1/sqrt(10)
  int b0 = (p >> 3) & 1, b1 = (p >> 2) & 1, b2 = (p >> 1) & 1, b3 = p & 1;
  re = (double)((1 - 2 * b0) * (2 - (1 - 2 * b2))) * s;
  im = (double)((1 - 2 * b1) * (2 - (1 - 2 * b3))) * s;
}

// ---------------- channel + LMMSE + max-log LLR --------------------------
// fp64 channel/Cholesky/solve (scalarized lower-triangular L); fp32 demap.
// Output Lch3[bt][pair][node][2]: contiguous float2 per codeword-pair.
__global__ void __launch_bounds__(256, 1)
k_lmmse(const float* __restrict__ h_re, const float* __restrict__ h_im,
        const float* __restrict__ n_re, const float* __restrict__ n_im,
        const double* __restrict__ nobuf, const int* __restrict__ symidx2,
        float* __restrict__ Lch3, int T, int ncw) {
  int t = blockIdx.x * blockDim.x + threadIdx.x;
  if (t >= T) return;
  int bt = t / NSYM, s = t - bt * NSYM;

  double no = nobuf[0];
  double sq = nobuf[1];
  const double is2 = 0.7071067811865475244;  // 1/sqrt(2)

  double Hr[4][4], Hi[4][4];
  {
    const float4* hr4 = (const float4*)h_re;
    const float4* hi4 = (const float4*)h_im;
    #pragma unroll
    for (int i = 0; i < 4; ++i) {
      float4 a = hr4[t * 4 + i], c = hi4[t * 4 + i];
      Hr[i][0] = (double)a.x * is2; Hr[i][1] = (double)a.y * is2;
      Hr[i][2] = (double)a.z * is2; Hr[i][3] = (double)a.w * is2;
      Hi[i][0] = (double)c.x * is2; Hi[i][1] = (double)c.y * is2;
      Hi[i][2] = (double)c.z * is2; Hi[i][3] = (double)c.w * is2;
    }
  }

  double xr[4], xi[4];
  {
    int4 ss = ((const int4*)symidx2)[bt * NSYM + s];
    qam_point(ss.x, xr[0], xi[0]);
    qam_point(ss.y, xr[1], xi[1]);
    qam_point(ss.z, xr[2], xi[2]);
    qam_point(ss.w, xr[3], xi[3]);
  }

  // y = H x + w
  double yr[4], yi[4];
  {
    float4 wr = ((const float4*)n_re)[t];
    float4 wi = ((const float4*)n_im)[t];
    float wrv[4] = {wr.x, wr.y, wr.z, wr.w};
    float wiv[4] = {wi.x, wi.y, wi.z, wi.w};
    #pragma unroll
    for (int i = 0; i < 4; ++i) {
      double ar = (double)wrv[i] * sq;
      double ai = (double)wiv[i] * sq;
      #pragma unroll
      for (int j = 0; j < 4; ++j) {
        ar += Hr[i][j] * xr[j] - Hi[i][j] * xi[j];
        ai += Hr[i][j] * xi[j] + Hi[i][j] * xr[j];
      }
      yr[i] = ar; yi[i] = ai;
    }
  }

  // A = H H^H + no I, lower triangle, into scalars
  auto dotc = [&](int i, int j, double& ar, double& ai) {
    double r = 0.0, m = 0.0;
    #pragma unroll
    for (int k = 0; k < 4; ++k) {
      r += Hr[i][k] * Hr[j][k] + Hi[i][k] * Hi[j][k];
      m += Hi[i][k] * Hr[j][k] - Hr[i][k] * Hi[j][k];
    }
    ar = r; ai = m;
  };
  double a00, a11, a22, a33, dum;
  double a10r, a10i, a20r, a20i, a21r, a21i, a30r, a30i, a31r, a31i, a32r, a32i;
  dotc(0, 0, a00, dum);  a00 += no;
  dotc(1, 0, a10r, a10i);
  dotc(1, 1, a11, dum);  a11 += no;
  dotc(2, 0, a20r, a20i);
  dotc(2, 1, a21r, a21i);
  dotc(2, 2, a22, dum);  a22 += no;
  dotc(3, 0, a30r, a30i);
  dotc(3, 1, a31r, a31i);
  dotc(3, 2, a32r, a32i);
  dotc(3, 3, a33, dum);  a33 += no;

  // Cholesky A = L L^H (scalarized)
  double L00 = sqrt(a00);
  double i00 = 1.0 / L00;
  double L10r = a10r * i00, L10i = a10i * i00;
  double L20r = a20r * i00, L20i = a20i * i00;
  double L30r = a30r * i00, L30i = a30i * i00;
  double L11 = sqrt(a11 - (L10r * L10r + L10i * L10i));
  double i11 = 1.0 / L11;
  double L21r = (a21r - (L20r * L10r + L20i * L10i)) * i11;
  double L21i = (a21i - (L20i * L10r - L20r * L10i)) * i11;
  double L31r = (a31r - (L30r * L10r + L30i * L10i)) * i11;
  double L31i = (a31i - (L30i * L10r - L30r * L10i)) * i11;
  double L22 = sqrt(a22 - (L20r * L20r + L20i * L20i) - (L21r * L21r + L21i * L21i));
  double i22 = 1.0 / L22;
  double L32r = (a32r - (L30r * L20r + L30i * L20i) - (L31r * L21r + L31i * L21i)) * i22;
  double L32i = (a32i - (L30i * L20r - L30r * L20i) - (L31i * L21r - L31r * L21i)) * i22;
  double L33 = sqrt(a33 - (L30r * L30r + L30i * L30i) - (L31r * L31r + L31i * L31i)
                        - (L32r * L32r + L32i * L32i));
  double i33 = 1.0 / L33;

  // forward solve: U = L^{-1} H (in place on H), v = L^{-1} y (in place on y)
  #pragma unroll
  for (int j = 0; j < 4; ++j) {
    double u0r = Hr[0][j] * i00,               u0i = Hi[0][j] * i00;
    double u1r = (Hr[1][j] - (L10r * u0r - L10i * u0i)) * i11;
    double u1i = (Hi[1][j] - (L10r * u0i + L10i * u0r)) * i11;
    double u2r = (Hr[2][j] - (L20r * u0r - L20i * u0i) - (L21r * u1r - L21i * u1i)) * i22;
    double u2i = (Hi[2][j] - (L20r * u0i + L20i * u0r) - (L21r * u1i + L21i * u1r)) * i22;
    double u3r = (Hr[3][j] - (L30r * u0r - L30i * u0i) - (L31r * u1r - L31i * u1i)
                           - (L32r * u2r - L32i * u2i)) * i33;
    double u3i = (Hi[3][j] - (L30r * u0i + L30i * u0r) - (L31r * u1i + L31i * u1r)
                           - (L32r * u2i + L32i * u2r)) * i33;
    Hr[0][j] = u0r; Hi[0][j] = u0i; Hr[1][j] = u1r; Hi[1][j] = u1i;
    Hr[2][j] = u2r; Hi[2][j] = u2i; Hr[3][j] = u3r; Hi[3][j] = u3i;
  }
  {
    double v0r = yr[0] * i00,               v0i = yi[0] * i00;
    double v1r = (yr[1] - (L10r * v0r - L10i * v0i)) * i11;
    double v1i = (yi[1] - (L10r * v0i + L10i * v0r)) * i11;
    double v2r = (yr[2] - (L20r * v0r - L20i * v0i) - (L21r * v1r - L21i * v1i)) * i22;
    double v2i = (yi[2] - (L20r * v0i + L20i * v0r) - (L21r * v1i + L21i * v1r)) * i22;
    double v3r = (yr[3] - (L30r * v0r - L30i * v0i) - (L31r * v1r - L31i * v1i)
                        - (L32r * v2r - L32i * v2i)) * i33;
    double v3i = (yi[3] - (L30r * v0i + L30i * v0r) - (L31r * v1i + L31i * v1r)
                        - (L32r * v2i + L32i * v2r)) * i33;
    yr[0] = v0r; yi[0] = v0i; yr[1] = v1r; yi[1] = v1i;
    yr[2] = v2r; yi[2] = v2i; yr[3] = v3r; yi[3] = v3i;
  }

  // fp32 16-QAM table
  const float PRT[16] = { 0.31622776601683794f, 0.31622776601683794f, 0.9486832980505138f, 0.9486832980505138f,
                          0.31622776601683794f, 0.31622776601683794f, 0.9486832980505138f, 0.9486832980505138f,
                         -0.31622776601683794f,-0.31622776601683794f,-0.9486832980505138f,-0.9486832980505138f,
                         -0.31622776601683794f,-0.31622776601683794f,-0.9486832980505138f,-0.9486832980505138f };
  const float PIT[16] = { 0.31622776601683794f, 0.9486832980505138f, 0.31622776601683794f, 0.9486832980505138f,
                         -0.31622776601683794f,-0.9486832980505138f,-0.31622776601683794f,-0.9486832980505138f,
                          0.31622776601683794f, 0.9486832980505138f, 0.31622776601683794f, 0.9486832980505138f,
                         -0.31622776601683794f,-0.9486832980505138f,-0.31622776601683794f,-0.9486832980505138f };

  float llr[4][4];  // [bit k][ue j]
  #pragma unroll
  for (int j = 0; j < 4; ++j) {
    double dj = 0.0, rr = 0.0, ri = 0.0;
    #pragma unroll
    for (int i = 0; i < 4; ++i) {
      dj += Hr[i][j] * Hr[i][j] + Hi[i][j] * Hi[i][j];
      rr += Hr[i][j] * yr[i] + Hi[i][j] * yi[i];
      ri += Hr[i][j] * yi[i] - Hi[i][j] * yr[i];
    }
    float xhr = (float)(rr / dj), xhi = (float)(ri / dj);
    float inoe = (float)(1.0 / fmax(1.0 / dj - 1.0, 1e-12));

    float m0[4] = {-1e30f, -1e30f, -1e30f, -1e30f};
    float m1[4] = {-1e30f, -1e30f, -1e30f, -1e30f};
    #pragma unroll
    for (int p = 0; p < 16; ++p) {
      float dr = xhr - PRT[p], di = xhi - PIT[p];
      float met = -(dr * dr + di * di) * inoe;
      #pragma unroll
      for (int k = 0; k < 4; ++k) {
        if ((p >> (3 - k)) & 1) m1[k] = fmaxf(m1[k], met);
        else                    m0[k] = fmaxf(m0[k], met);
      }
    }
    #pragma unroll
    for (int k = 0; k < 4; ++k) llr[k][j] = m0[k] - m1[k];
  }

  // store: plane 0 = ue{0,1}, plane 1 = ue{2,3}
  float2* pl0 = (float2*)(Lch3 + (size_t)bt * (NNODES * 4));
  float2* pl1 = pl0 + NNODES;
  #pragma unroll
  for (int k = 0; k < 4; ++k) {
    int node = 4 * s + k;
    pl0[node] = make_float2(llr[k][0], llr[k][1]);
    pl1[node] = make_float2(llr[k][2], llr[k][3]);
  }
}

// ---------------- fused LDS-resident BP decoder, 2 codewords / block --------
// w-domain formulation: all per-iteration transcendentals eliminated.
//   t = tanh(v2c/2) = (w-1)/(w+1),  w = exp(v2c) = E * W_a * W_b,
//   E = exp(L) (preamble, clipped),  W = (1+r)/(1-r), r = clip(P/t).
// The w-clamp to e^{+-19.8} reproduces the reference's +-9.9 clip; the
// r-clip +-0.999999 and the 1e-7 tanh floor are applied identically.
__device__ __forceinline__ float tanh_half(float m) {
  float mc = fminf(fmaxf(m, -19.8f), 19.8f);
  float e = __expf(mc);
  float t = 1.0f - __fdividef(2.0f, e + 1.0f);
  return (t >= 0.0f) ? fmaxf(t, 1e-7f) : fminf(t, -1e-7f);
}

__device__ __forceinline__ float ratioW(float P, float t) {
  // W = (1+r)/(1-r), r = clip(P/t, +-0.999999)  ==  exp(2*atanh(clip(r)))
  float r = __fdividef(P, t);
  r = fminf(fmaxf(r, -0.999999f), 0.999999f);
  return __fdividef(1.0f + r, 1.0f - r);
}

__device__ __forceinline__ float t_from_w(float w) {
  // tanh of clipped message: clamp w to e^{+-19.8}, t = (w-1)/(w+1), 1e-7 floor
  w = fminf(fmaxf(w, 2.5109992e-9f), 3.9824784e8f);
  float t = __fdividef(w - 1.0f, w + 1.0f);
  return (t >= 0.0f) ? fmaxf(t, 1e-7f) : fminf(t, -1e-7f);
}

__device__ __forceinline__ float atanh2c(float P, float t) {
  float r = __fdividef(P, t);
  r = fminf(fmaxf(r, -0.999999f), 0.999999f);
  return __logf(__fdividef(1.0f + r, 1.0f - r));
}

__global__ void __launch_bounds__(256) k_bp(const float* __restrict__ Lch3,
                                            const int* __restrict__ vlist,
                                            const int* __restrict__ coff,
                                            const int* __restrict__ cinfo,
                                            float* __restrict__ out, int E, int ncw) {
  __shared__ float2 sL[NNODES];   // channel LLRs
  __shared__ float2 sT[EMAX];     // tanh(v2c/2) per edge slot
  __shared__ float2 sP[512];      // per-check product of tanh

  int tid = threadIdx.x;
  int pairId = blockIdx.x;  // = bt*2 + plane; codewords 2*pairId, 2*pairId+1

  const float2* src = (const float2*)(Lch3 + (size_t)pairId * (NNODES * 2));
  float2 En[2];  // exp(clip(L,+-55)) per owned info node
  #pragma unroll
  for (int i = 0; i < 4; ++i) {
    int n = tid + TB * i;
    if (n < NNODES) {
      float2 L = src[n];
      sL[n] = L;
      if (i < 2 && n < KK)
        En[i] = make_float2(__expf(fminf(fmaxf(L.x, -55.f), 55.f)),
                            __expf(fminf(fmaxf(L.y, -55.f), 55.f)));
    }
  }

  // parity-node constant tanh (degree 1: v2c == L forever)
  #pragma unroll
  for (int i = 0; i < 2; ++i) {
    int n = KK + tid + TB * i;
    if (n < NNODES) {
      int slot = vlist[n * MAXVDEG];
      float2 L = src[n];
      sT[slot] = make_float2(tanh_half(L.x), tanh_half(L.y));
    }
  }

  // register cache: per info node, 3 packed (check<<16)|slot
  int pk0[2], pk1[2], pk2[2]; bool iok[2];
  #pragma unroll
  for (int i = 0; i < 2; ++i) {
    int n = tid + TB * i;
    iok[i] = n < KK;
    pk0[i] = pk1[i] = pk2[i] = 0;
    if (iok[i]) {
      int s0 = vlist[n * MAXVDEG], s1 = vlist[n * MAXVDEG + 1], s2 = vlist[n * MAXVDEG + 2];
      pk0[i] = (cinfo[s0] & 0xffff0000) | s0;
      pk1[i] = (cinfo[s1] & 0xffff0000) | s1;
      pk2[i] = (cinfo[s2] & 0xffff0000) | s2;
    }
  }
  int beg0 = coff[tid], end0 = coff[tid + 1];
  bool c1ok = (tid + TB) < MM;
  int beg1 = c1ok ? coff[tid + TB] : 0;
  int end1 = c1ok ? coff[tid + TB + 1] : 0;
  __syncthreads();

  for (int it = 0; it < NITERS; ++it) {
    // ---- pass 1: info-node var update (w-domain, no transcendentals) ----
    if (it == 0) {
      #pragma unroll
      for (int i = 0; i < 2; ++i) {
        if (iok[i]) {
          int n = tid + TB * i;
          float2 L = sL[n];
          float2 t = make_float2(tanh_half(L.x), tanh_half(L.y));
          sT[pk0[i] & 0xffff] = t;
          sT[pk1[i] & 0xffff] = t;
          sT[pk2[i] & 0xffff] = t;
        }
      }
    } else {
      #pragma unroll
      for (int i = 0; i < 2; ++i) {
        if (iok[i]) {
          int s0 = pk0[i] & 0xffff, c0 = ((unsigned)pk0[i]) >> 16;
          int s1 = pk1[i] & 0xffff, c1 = ((unsigned)pk1[i]) >> 16;
          int s2 = pk2[i] & 0xffff, c2 = ((unsigned)pk2[i]) >> 16;
          float2 P0 = sP[c0], P1 = sP[c1], P2 = sP[c2];
          float2 t0 = sT[s0], t1 = sT[s1], t2 = sT[s2];
          float W0x = ratioW(P0.x, t0.x), W0y = ratioW(P0.y, t0.y);
          float W1x = ratioW(P1.x, t1.x), W1y = ratioW(P1.y, t1.y);
          float W2x = ratioW(P2.x, t2.x), W2y = ratioW(P2.y, t2.y);
          float Ex = En[i].x, Ey = En[i].y;
          sT[s0] = make_float2(t_from_w(Ex * W1x * W2x), t_from_w(Ey * W1y * W2y));
          sT[s1] = make_float2(t_from_w(Ex * W0x * W2x), t_from_w(Ey * W0y * W2y));
          sT[s2] = make_float2(t_from_w(Ex * W0x * W1x), t_from_w(Ey * W0y * W1y));
        }
      }
    }
    __syncthreads();
    // ---- pass 2: per-check products ----
    {
      float px = 1.0f, py = 1.0f;
      for (int e = beg0; e < end0; ++e) { float2 tt = sT[e]; px *= tt.x; py *= tt.y; }
      sP[tid] = make_float2(px, py);
      if (c1ok) {
        float qx = 1.0f, qy = 1.0f;
        for (int e = beg1; e < end1; ++e) { float2 tt = sT[e]; qx *= tt.x; qy *= tt.y; }
        sP[tid + TB] = make_float2(qx, qy);
      }
    }
    __syncthreads();
  }

  // ---- decide: additive log form (3 logs per node, once) ----
  int cw0 = pairId * 2;
  float* o0 = out + (size_t)ncw * KK + (size_t)cw0 * KK;
  float* o1 = o0 + KK;
  #pragma unroll
  for (int i = 0; i < 2; ++i) {
    if (iok[i]) {
      int n = tid + TB * i;
      int s0 = pk0[i] & 0xffff, c0 = ((unsigned)pk0[i]) >> 16;
      int s1 = pk1[i] & 0xffff, c1 = ((unsigned)pk1[i]) >> 16;
      int s2 = pk2[i] & 0xffff, c2 = ((unsigned)pk2[i]) >> 16;
      float2 P0 = sP[c0], P1 = sP[c1], P2 = sP[c2];
      float2 t0 = sT[s0], t1 = sT[s1], t2 = sT[s2];
      float2 L = sL[n];
      float ax = L.x + atanh2c(P0.x, t0.x) + atanh2c(P1.x, t1.x) + atanh2c(P2.x, t2.x);
      float ay = L.y + atanh2c(P0.y, t0.y) + atanh2c(P1.y, t1.y) + atanh2c(P2.y, t2.y);
      o0[n] = (ax < 0.0f) ? 1.0f : 0.0f;
      o1[n] = (ay < 0.0f) ? 1.0f : 0.0f;
    }
  }
}

// ---------------- launcher ----------------
extern "C" void kernel_launch(void* const* d_in, const int* in_sizes, int n_in,
                              void* d_out, int out_size, void* d_ws, size_t ws_size,
                              hipStream_t stream) {
  const float* ebno = (const float*)d_in[1];
  const int*   b    = (const int*)d_in[2];
  const int*   P    = (const int*)d_in[3];
  const int*   cn   = (const int*)d_in[4];
  const int*   vn   = (const int*)d_in[5];
  const float* h_re = (const float*)d_in[6];
  const float* h_im = (const float*)d_in[7];
  const float* nre  = (const float*)d_in[8];
  const float* nim  = (const float*)d_in[9];
  float* out = (float*)d_out;

  int E     = in_sizes[4];
  int batch = in_sizes[2] / (4 * KK);
  int ncw   = batch * 4;
  int T     = batch * NSYM;

  char* ws = (char*)d_ws;
  size_t off = 0;
  auto alloc = [&](size_t bytes) -> void* {
    void* p = ws + off;
    off += (bytes + 255) & ~(size_t)255;
    return p;
  };
  float*    Lch3   = (float*)alloc((size_t)NNODES * ncw * 4);
  int*      symidx = (int*)alloc((size_t)ncw * NSYM * 4);
  unsigned* Ppack  = (unsigned*)alloc((size_t)MM * 16 * 4);
  unsigned* bpack  = (unsigned*)alloc((size_t)ncw * 16 * 4);
  int*      coff   = (int*)alloc((size_t)(MM + 1) * 4);
  int*      cinfo  = (int*)alloc((size_t)EMAX * 4);
  int*      vlist  = (int*)alloc((size_t)NNODES * MAXVDEG * 4);
  double*   nobuf  = (double*)alloc(2 * 8);
  (void)ws_size; (void)n_in; (void)out_size;

  const int tb = 256;
  k_graph<<<dim3(1), dim3(512), 0, stream>>>(cn, vn, E, ebno, cinfo, vlist, coff, nobuf);
  {
    int tot = MM * 16 + ncw * 16;
    k_pack<<<dim3((tot + tb - 1) / tb), dim3(tb), 0, stream>>>(P, b, Ppack, bpack, ncw);
  }
  {
    int tot = ncw * KK + ncw * NSYM;
    k_symbf<<<dim3((tot + tb - 1) / tb), dim3(tb), 0, stream>>>(bpack, Ppack, b, out, symidx, ncw);
  }
  k_lmmse<<<dim3((T + tb - 1) / tb), dim3(tb), 0, stream>>>(h_re, h_im, nre, nim, nobuf, symidx, Lch3, T, ncw);
  k_bp<<<dim3(ncw / 2), dim3(tb), 0, stream>>>(Lch3, vlist, coff, cinfo, out, E, ncw);
}

// Round 10
// 208.414 us; speedup vs baseline: 1.2870x; 1.0183x over previous
//
#include <hip/hip_runtime.h>
#include <math.h>

// Problem constants (from reference)
#define KK     500   // info bits
#define MM     500   // parity checks
#define NNODES 1000  // N = K + M variable nodes
#define NSYM   250   // N / BPS
#define NITERS 5
#define MAXVDEG 4    // info vars degree exactly 3 (row weight of P), parity vars 1
#define EMAX   2048  // E = 2000 edges
#define TB     256

// ---------------- setup: graph build + bit packing + bf output -------------
// block 0: graph (count -> LDS scan -> fill) + noise scalar
// blocks 1..packBlocks: pack P columns / codeword bits
// remaining blocks: bf = float(b) output copy
__global__ void __launch_bounds__(512)
k_setup(const int* __restrict__ cn, const int* __restrict__ vn, int E,
        const float* __restrict__ ebno, const int* __restrict__ P,
        const int* __restrict__ b, int ncw,
        int* __restrict__ cinfo, int* __restrict__ vlist, int* __restrict__ coff,
        double* __restrict__ nobuf, unsigned* __restrict__ Ppack,
        unsigned* __restrict__ bpack, float* __restrict__ out, int packBlocks) {
  __shared__ int sdeg[512];
  __shared__ int ssc[512];
  __shared__ int scur[512];
  __shared__ int svc[NNODES];
  int tid = threadIdx.x;
  int bx = blockIdx.x;

  if (bx == 0) {
    sdeg[tid] = 0;
    for (int n = tid; n < NNODES; n += 512) svc[n] = 0;
    __syncthreads();
    for (int e = tid; e < E; e += 512) atomicAdd(&sdeg[cn[e]], 1);
    __syncthreads();
    int v = sdeg[tid];
    ssc[tid] = v;
    __syncthreads();
    for (int o = 1; o < 512; o <<= 1) {
      int x = (tid >= o) ? ssc[tid - o] : 0;
      __syncthreads();
      ssc[tid] += x;
      __syncthreads();
    }
    int excl = ssc[tid] - v;
    scur[tid] = excl;
    if (tid < MM) {
      coff[tid] = excl;
      if (tid == MM - 1) coff[MM] = ssc[tid];
    }
    __syncthreads();
    for (int e = tid; e < E; e += 512) {
      int c = cn[e], n = vn[e];
      int slot = atomicAdd(&scur[c], 1);
      cinfo[slot] = (c << 16) | n;
      int t = atomicAdd(&svc[n], 1);
      if (t < MAXVDEG) vlist[n * MAXVDEG + t] = slot;
    }
    if (tid == 0) {
      double no = 1.0 / (pow(10.0, (double)ebno[0] * 0.1) * 2.0);  // BPS*RATE = 2
      nobuf[0] = no;
      nobuf[1] = sqrt(no * 0.5);
    }
    return;
  }

  if (bx <= packBlocks) {
    int id = (bx - 1) * 512 + tid;
    if (id < MM * 16) {
      int j = id >> 4, w = id & 15;
      unsigned word = 0u;
      int base = w * 32;
      for (int bit = 0; bit < 32; ++bit) {
        int i = base + bit;
        if (i < KK && P[i * MM + j] != 0) word |= (1u << bit);
      }
      Ppack[j * 16 + w] = word;
    } else {
      int id2 = id - MM * 16;
      if (id2 < ncw * 16) {
        int cw = id2 >> 4, w = id2 & 15;
        unsigned word = 0u;
        int base = w * 32;
        for (int bit = 0; bit < 32; ++bit) {
          int i = base + bit;
          if (i < KK && b[cw * KK + i] != 0) word |= (1u << bit);
        }
        bpack[cw * 16 + w] = word;
      }
    }
    return;
  }

  int id = (bx - 1 - packBlocks) * 512 + tid;
  if (id < ncw * KK) out[id] = (float)b[id];
}

// ---------------- 16-QAM constellation (fp64 for TX symbol) ----------------
__device__ __forceinline__ void qam_point(int p, double& re, double& im) {
  const double s = 0.31622776601683794;  // 1/sqrt(10)
  int b0 = (p >> 3) & 1, b1 = (p >> 2) & 1, b2 = (p >> 1) & 1, b3 = p & 1;
  re = (double)((1 - 2 * b0) * (2 - (1 - 2 * b2))) * s;
  im = (double)((1 - 2 * b1) * (2 - (1 - 2 * b3))) * s;
}

// ---------------- channel + LMMSE + max-log LLR --------------------------
// Symbols computed INLINE from bpack/Ppack (no symidx buffer / dispatch).
// fp64 channel/Cholesky/solve (scalarized); fp32 demap.
// Output Lch2[bt][node][ue0..3]: one float4 per node, coalesced store.
__global__ void __launch_bounds__(256, 1)
k_lmmse(const float* __restrict__ h_re, const float* __restrict__ h_im,
        const float* __restrict__ n_re, const float* __restrict__ n_im,
        const double* __restrict__ nobuf,
        const unsigned* __restrict__ bpack, const unsigned* __restrict__ Ppack,
        float* __restrict__ Lch2, int T, int ncw) {
  int t = blockIdx.x * blockDim.x + threadIdx.x;
  if (t >= T) return;
  int bt = t / NSYM, s = t - bt * NSYM;

  double no = nobuf[0];
  double sq = nobuf[1];
  const double is2 = 0.7071067811865475244;  // 1/sqrt(2)

  double Hr[4][4], Hi[4][4];
  {
    const float4* hr4 = (const float4*)h_re;
    const float4* hi4 = (const float4*)h_im;
    #pragma unroll
    for (int i = 0; i < 4; ++i) {
      float4 a = hr4[t * 4 + i], c = hi4[t * 4 + i];
      Hr[i][0] = (double)a.x * is2; Hr[i][1] = (double)a.y * is2;
      Hr[i][2] = (double)a.z * is2; Hr[i][3] = (double)a.w * is2;
      Hi[i][0] = (double)c.x * is2; Hi[i][1] = (double)c.y * is2;
      Hi[i][2] = (double)c.z * is2; Hi[i][3] = (double)c.w * is2;
    }
  }

  // transmitted symbols: encode+map inline
  double xr[4], xi[4];
  #pragma unroll
  for (int ue = 0; ue < 4; ++ue) {
    const unsigned* bp = bpack + (bt * 4 + ue) * 16;
    int v = 0;
    #pragma unroll
    for (int k = 0; k < 4; ++k) {
      int n = 4 * s + k;
      int bit;
      if (n < KK) {
        bit = (bp[n >> 5] >> (n & 31)) & 1;
      } else {
        const unsigned* pp = Ppack + (n - KK) * 16;
        int cnt = 0;
        #pragma unroll
        for (int w = 0; w < 16; ++w) cnt += __popc(bp[w] & pp[w]);
        bit = cnt & 1;
      }
      v = (v << 1) | bit;  // MSB-first: weights 8,4,2,1
    }
    qam_point(v, xr[ue], xi[ue]);
  }

  // y = H x + w
  double yr[4], yi[4];
  {
    float4 wr = ((const float4*)n_re)[t];
    float4 wi = ((const float4*)n_im)[t];
    float wrv[4] = {wr.x, wr.y, wr.z, wr.w};
    float wiv[4] = {wi.x, wi.y, wi.z, wi.w};
    #pragma unroll
    for (int i = 0; i < 4; ++i) {
      double ar = (double)wrv[i] * sq;
      double ai = (double)wiv[i] * sq;
      #pragma unroll
      for (int j = 0; j < 4; ++j) {
        ar += Hr[i][j] * xr[j] - Hi[i][j] * xi[j];
        ai += Hr[i][j] * xi[j] + Hi[i][j] * xr[j];
      }
      yr[i] = ar; yi[i] = ai;
    }
  }

  // A = H H^H + no I, lower triangle, into scalars
  auto dotc = [&](int i, int j, double& ar, double& ai) {
    double r = 0.0, m = 0.0;
    #pragma unroll
    for (int k = 0; k < 4; ++k) {
      r += Hr[i][k] * Hr[j][k] + Hi[i][k] * Hi[j][k];
      m += Hi[i][k] * Hr[j][k] - Hr[i][k] * Hi[j][k];
    }
    ar = r; ai = m;
  };
  double a00, a11, a22, a33, dum;
  double a10r, a10i, a20r, a20i, a21r, a21i, a30r, a30i, a31r, a31i, a32r, a32i;
  dotc(0, 0, a00, dum);  a00 += no;
  dotc(1, 0, a10r, a10i);
  dotc(1, 1, a11, dum);  a11 += no;
  dotc(2, 0, a20r, a20i);
  dotc(2, 1, a21r, a21i);
  dotc(2, 2, a22, dum);  a22 += no;
  dotc(3, 0, a30r, a30i);
  dotc(3, 1, a31r, a31i);
  dotc(3, 2, a32r, a32i);
  dotc(3, 3, a33, dum);  a33 += no;

  // Cholesky A = L L^H (scalarized)
  double L00 = sqrt(a00);
  double i00 = 1.0 / L00;
  double L10r = a10r * i00, L10i = a10i * i00;
  double L20r = a20r * i00, L20i = a20i * i00;
  double L30r = a30r * i00, L30i = a30i * i00;
  double L11 = sqrt(a11 - (L10r * L10r + L10i * L10i));
  double i11 = 1.0 / L11;
  double L21r = (a21r - (L20r * L10r + L20i * L10i)) * i11;
  double L21i = (a21i - (L20i * L10r - L20r * L10i)) * i11;
  double L31r = (a31r - (L30r * L10r + L30i * L10i)) * i11;
  double L31i = (a31i - (L30i * L10r - L30r * L10i)) * i11;
  double L22 = sqrt(a22 - (L20r * L20r + L20i * L20i) - (L21r * L21r + L21i * L21i));
  double i22 = 1.0 / L22;
  double L32r = (a32r - (L30r * L20r + L30i * L20i) - (L31r * L21r + L31i * L21i)) * i22;
  double L32i = (a32i - (L30i * L20r - L30r * L20i) - (L31i * L21r - L31r * L21i)) * i22;
  double L33 = sqrt(a33 - (L30r * L30r + L30i * L30i) - (L31r * L31r + L31i * L31i)
                        - (L32r * L32r + L32i * L32i));
  double i33 = 1.0 / L33;

  // forward solve: U = L^{-1} H (in place on H), v = L^{-1} y (in place on y)
  #pragma unroll
  for (int j = 0; j < 4; ++j) {
    double u0r = Hr[0][j] * i00,               u0i = Hi[0][j] * i00;
    double u1r = (Hr[1][j] - (L10r * u0r - L10i * u0i)) * i11;
    double u1i = (Hi[1][j] - (L10r * u0i + L10i * u0r)) * i11;
    double u2r = (Hr[2][j] - (L20r * u0r - L20i * u0i) - (L21r * u1r - L21i * u1i)) * i22;
    double u2i = (Hi[2][j] - (L20r * u0i + L20i * u0r) - (L21r * u1i + L21i * u1r)) * i22;
    double u3r = (Hr[3][j] - (L30r * u0r - L30i * u0i) - (L31r * u1r - L31i * u1i)
                           - (L32r * u2r - L32i * u2i)) * i33;
    double u3i = (Hi[3][j] - (L30r * u0i + L30i * u0r) - (L31r * u1i + L31i * u1r)
                           - (L32r * u2i + L32i * u2r)) * i33;
    Hr[0][j] = u0r; Hi[0][j] = u0i; Hr[1][j] = u1r; Hi[1][j] = u1i;
    Hr[2][j] = u2r; Hi[2][j] = u2i; Hr[3][j] = u3r; Hi[3][j] = u3i;
  }
  {
    double v0r = yr[0] * i00,               v0i = yi[0] * i00;
    double v1r = (yr[1] - (L10r * v0r - L10i * v0i)) * i11;
    double v1i = (yi[1] - (L10r * v0i + L10i * v0r)) * i11;
    double v2r = (yr[2] - (L20r * v0r - L20i * v0i) - (L21r * v1r - L21i * v1i)) * i22;
    double v2i = (yi[2] - (L20r * v0i + L20i * v0r) - (L21r * v1i + L21i * v1r)) * i22;
    double v3r = (yr[3] - (L30r * v0r - L30i * v0i) - (L31r * v1r - L31i * v1i)
                        - (L32r * v2r - L32i * v2i)) * i33;
    double v3i = (yi[3] - (L30r * v0i + L30i * v0r) - (L31r * v1i + L31i * v1r)
                        - (L32r * v2i + L32i * v2r)) * i33;
    yr[0] = v0r; yi[0] = v0i; yr[1] = v1r; yi[1] = v1i;
    yr[2] = v2r; yi[2] = v2i; yr[3] = v3r; yi[3] = v3i;
  }

  // fp32 16-QAM table
  const float PRT[16] = { 0.31622776601683794f, 0.31622776601683794f, 0.9486832980505138f, 0.9486832980505138f,
                          0.31622776601683794f, 0.31622776601683794f, 0.9486832980505138f, 0.9486832980505138f,
                         -0.31622776601683794f,-0.31622776601683794f,-0.9486832980505138f,-0.9486832980505138f,
                         -0.31622776601683794f,-0.31622776601683794f,-0.9486832980505138f,-0.9486832980505138f };
  const float PIT[16] = { 0.31622776601683794f, 0.9486832980505138f, 0.31622776601683794f, 0.9486832980505138f,
                         -0.31622776601683794f,-0.9486832980505138f,-0.31622776601683794f,-0.9486832980505138f,
                          0.31622776601683794f, 0.9486832980505138f, 0.31622776601683794f, 0.9486832980505138f,
                         -0.31622776601683794f,-0.9486832980505138f,-0.31622776601683794f,-0.9486832980505138f };

  float llr[4][4];  // [bit k][ue j]
  #pragma unroll
  for (int j = 0; j < 4; ++j) {
    double dj = 0.0, rr = 0.0, ri = 0.0;
    #pragma unroll
    for (int i = 0; i < 4; ++i) {
      dj += Hr[i][j] * Hr[i][j] + Hi[i][j] * Hi[i][j];
      rr += Hr[i][j] * yr[i] + Hi[i][j] * yi[i];
      ri += Hr[i][j] * yi[i] - Hi[i][j] * yr[i];
    }
    float xhr = (float)(rr / dj), xhi = (float)(ri / dj);
    float inoe = (float)(1.0 / fmax(1.0 / dj - 1.0, 1e-12));

    float m0[4] = {-1e30f, -1e30f, -1e30f, -1e30f};
    float m1[4] = {-1e30f, -1e30f, -1e30f, -1e30f};
    #pragma unroll
    for (int p = 0; p < 16; ++p) {
      float dr = xhr - PRT[p], di = xhi - PIT[p];
      float met = -(dr * dr + di * di) * inoe;
      #pragma unroll
      for (int k = 0; k < 4; ++k) {
        if ((p >> (3 - k)) & 1) m1[k] = fmaxf(m1[k], met);
        else                    m0[k] = fmaxf(m0[k], met);
      }
    }
    #pragma unroll
    for (int k = 0; k < 4; ++k) llr[k][j] = m0[k] - m1[k];
  }

  // store: one float4 (all 4 UEs) per node, contiguous per thread
  float4* dst = (float4*)(Lch2 + (size_t)bt * (NNODES * 4)) + 4 * s;
  #pragma unroll
  for (int k = 0; k < 4; ++k)
    dst[k] = make_float4(llr[k][0], llr[k][1], llr[k][2], llr[k][3]);
}

// ---------------- fused LDS-resident BP decoder, 4 codewords / block --------
// w-domain formulation (no per-iteration transcendentals); see round-8 notes.
__device__ __forceinline__ float tanh_half(float m) {
  float mc = fminf(fmaxf(m, -19.8f), 19.8f);
  float e = __expf(mc);
  float t = 1.0f - __fdividef(2.0f, e + 1.0f);
  return (t >= 0.0f) ? fmaxf(t, 1e-7f) : fminf(t, -1e-7f);
}
__device__ __forceinline__ float ratioW(float P, float t) {
  float r = __fdividef(P, t);
  r = fminf(fmaxf(r, -0.999999f), 0.999999f);
  return __fdividef(1.0f + r, 1.0f - r);
}
__device__ __forceinline__ float t_from_w(float w) {
  w = fminf(fmaxf(w, 2.5109992e-9f), 3.9824784e8f);
  float t = __fdividef(w - 1.0f, w + 1.0f);
  return (t >= 0.0f) ? fmaxf(t, 1e-7f) : fminf(t, -1e-7f);
}
__device__ __forceinline__ float atanh2c(float P, float t) {
  float r = __fdividef(P, t);
  r = fminf(fmaxf(r, -0.999999f), 0.999999f);
  return __logf(__fdividef(1.0f + r, 1.0f - r));
}
__device__ __forceinline__ float4 tanh_half4(float4 m) {
  return make_float4(tanh_half(m.x), tanh_half(m.y), tanh_half(m.z), tanh_half(m.w));
}
__device__ __forceinline__ float4 ratioW4(float4 P, float4 t) {
  return make_float4(ratioW(P.x, t.x), ratioW(P.y, t.y), ratioW(P.z, t.z), ratioW(P.w, t.w));
}
__device__ __forceinline__ float4 tw4(float4 E, float4 A, float4 B) {
  return make_float4(t_from_w(E.x * A.x * B.x), t_from_w(E.y * A.y * B.y),
                     t_from_w(E.z * A.z * B.z), t_from_w(E.w * A.w * B.w));
}

// One block = one BATCH element = 4 codewords (same Tanner graph).
__global__ void __launch_bounds__(256) k_bp(const float* __restrict__ Lch2,
                                            const int* __restrict__ vlist,
                                            const int* __restrict__ coff,
                                            const int* __restrict__ cinfo,
                                            float* __restrict__ out, int E, int ncw) {
  __shared__ float4 sL[NNODES];   // channel LLRs (4 codewords)
  __shared__ float4 sT[EMAX];     // tanh(v2c/2) per edge slot
  __shared__ float4 sP[512];      // per-check product of tanh

  int tid = threadIdx.x;
  int bt = blockIdx.x;  // codewords 4*bt .. 4*bt+3

  const float4* src = (const float4*)(Lch2 + (size_t)bt * (NNODES * 4));
  float4 En[2];  // exp(clip(L,+-55)) per owned info node
  #pragma unroll
  for (int i = 0; i < 4; ++i) {
    int n = tid + TB * i;
    if (n < NNODES) {
      float4 L = src[n];
      sL[n] = L;
      if (i < 2 && n < KK)
        En[i] = make_float4(__expf(fminf(fmaxf(L.x, -55.f), 55.f)),
                            __expf(fminf(fmaxf(L.y, -55.f), 55.f)),
                            __expf(fminf(fmaxf(L.z, -55.f), 55.f)),
                            __expf(fminf(fmaxf(L.w, -55.f), 55.f)));
    }
  }

  // parity-node constant tanh (degree 1: v2c == L forever)
  #pragma unroll
  for (int i = 0; i < 2; ++i) {
    int n = KK + tid + TB * i;
    if (n < NNODES) {
      int slot = vlist[n * MAXVDEG];
      sT[slot] = tanh_half4(src[n]);
    }
  }

  // register cache: per info node, 3 packed (check<<16)|slot
  int pk0[2], pk1[2], pk2[2]; bool iok[2];
  #pragma unroll
  for (int i = 0; i < 2; ++i) {
    int n = tid + TB * i;
    iok[i] = n < KK;
    pk0[i] = pk1[i] = pk2[i] = 0;
    if (iok[i]) {
      int s0 = vlist[n * MAXVDEG], s1 = vlist[n * MAXVDEG + 1], s2 = vlist[n * MAXVDEG + 2];
      pk0[i] = (cinfo[s0] & 0xffff0000) | s0;
      pk1[i] = (cinfo[s1] & 0xffff0000) | s1;
      pk2[i] = (cinfo[s2] & 0xffff0000) | s2;
    }
  }
  int beg0 = coff[tid], end0 = coff[tid + 1];
  bool c1ok = (tid + TB) < MM;
  int beg1 = c1ok ? coff[tid + TB] : 0;
  int end1 = c1ok ? coff[tid + TB + 1] : 0;
  __syncthreads();

  for (int it = 0; it < NITERS; ++it) {
    // ---- pass 1: info-node var update (w-domain) ----
    if (it == 0) {
      #pragma unroll
      for (int i = 0; i < 2; ++i) {
        if (iok[i]) {
          int n = tid + TB * i;
          float4 t = tanh_half4(sL[n]);
          sT[pk0[i] & 0xffff] = t;
          sT[pk1[i] & 0xffff] = t;
          sT[pk2[i] & 0xffff] = t;
        }
      }
    } else {
      #pragma unroll
      for (int i = 0; i < 2; ++i) {
        if (iok[i]) {
          int s0 = pk0[i] & 0xffff, c0 = ((unsigned)pk0[i]) >> 16;
          int s1 = pk1[i] & 0xffff, c1 = ((unsigned)pk1[i]) >> 16;
          int s2 = pk2[i] & 0xffff, c2 = ((unsigned)pk2[i]) >> 16;
          float4 W0 = ratioW4(sP[c0], sT[s0]);
          float4 W1 = ratioW4(sP[c1], sT[s1]);
          float4 W2 = ratioW4(sP[c2], sT[s2]);
          float4 Ev = En[i];
          sT[s0] = tw4(Ev, W1, W2);
          sT[s1] = tw4(Ev, W0, W2);
          sT[s2] = tw4(Ev, W0, W1);
        }
      }
    }
    __syncthreads();
    // ---- pass 2: per-check products ----
    {
      float px = 1.0f, py = 1.0f, pz = 1.0f, pw = 1.0f;
      for (int e = beg0; e < end0; ++e) {
        float4 tt = sT[e];
        px *= tt.x; py *= tt.y; pz *= tt.z; pw *= tt.w;
      }
      sP[tid] = make_float4(px, py, pz, pw);
      if (c1ok) {
        float qx = 1.0f, qy = 1.0f, qz = 1.0f, qw = 1.0f;
        for (int e = beg1; e < end1; ++e) {
          float4 tt = sT[e];
          qx *= tt.x; qy *= tt.y; qz *= tt.z; qw *= tt.w;
        }
        sP[tid + TB] = make_float4(qx, qy, qz, qw);
      }
    }
    __syncthreads();
  }

  // ---- decide: additive log form (once) ----
  float* o0 = out + (size_t)ncw * KK + (size_t)(bt * 4) * KK;
  float* o1 = o0 + KK;
  float* o2 = o1 + KK;
  float* o3 = o2 + KK;
  #pragma unroll
  for (int i = 0; i < 2; ++i) {
    if (iok[i]) {
      int n = tid + TB * i;
      int s0 = pk0[i] & 0xffff, c0 = ((unsigned)pk0[i]) >> 16;
      int s1 = pk1[i] & 0xffff, c1 = ((unsigned)pk1[i]) >> 16;
      int s2 = pk2[i] & 0xffff, c2 = ((unsigned)pk2[i]) >> 16;
      float4 P0 = sP[c0], P1 = sP[c1], P2 = sP[c2];
      float4 t0 = sT[s0], t1 = sT[s1], t2 = sT[s2];
      float4 L = sL[n];
      float ax = L.x + atanh2c(P0.x, t0.x) + atanh2c(P1.x, t1.x) + atanh2c(P2.x, t2.x);
      float ay = L.y + atanh2c(P0.y, t0.y) + atanh2c(P1.y, t1.y) + atanh2c(P2.y, t2.y);
      float az = L.z + atanh2c(P0.z, t0.z) + atanh2c(P1.z, t1.z) + atanh2c(P2.z, t2.z);
      float aw = L.w + atanh2c(P0.w, t0.w) + atanh2c(P1.w, t1.w) + atanh2c(P2.w, t2.w);
      o0[n] = (ax < 0.0f) ? 1.0f : 0.0f;
      o1[n] = (ay < 0.0f) ? 1.0f : 0.0f;
      o2[n] = (az < 0.0f) ? 1.0f : 0.0f;
      o3[n] = (aw < 0.0f) ? 1.0f : 0.0f;
    }
  }
}

// ---------------- launcher ----------------
extern "C" void kernel_launch(void* const* d_in, const int* in_sizes, int n_in,
                              void* d_out, int out_size, void* d_ws, size_t ws_size,
                              hipStream_t stream) {
  const float* ebno = (const float*)d_in[1];
  const int*   b    = (const int*)d_in[2];
  const int*   P    = (const int*)d_in[3];
  const int*   cn   = (const int*)d_in[4];
  const int*   vn   = (const int*)d_in[5];
  const float* h_re = (const float*)d_in[6];
  const float* h_im = (const float*)d_in[7];
  const float* nre  = (const float*)d_in[8];
  const float* nim  = (const float*)d_in[9];
  float* out = (float*)d_out;

  int E     = in_sizes[4];
  int batch = in_sizes[2] / (4 * KK);
  int ncw   = batch * 4;
  int T     = batch * NSYM;

  char* ws = (char*)d_ws;
  size_t off = 0;
  auto alloc = [&](size_t bytes) -> void* {
    void* p = ws + off;
    off += (bytes + 255) & ~(size_t)255;
    return p;
  };
  float*    Lch2   = (float*)alloc((size_t)NNODES * ncw * 4);
  unsigned* Ppack  = (unsigned*)alloc((size_t)MM * 16 * 4);
  unsigned* bpack  = (unsigned*)alloc((size_t)ncw * 16 * 4);
  int*      coff   = (int*)alloc((size_t)(MM + 1) * 4);
  int*      cinfo  = (int*)alloc((size_t)EMAX * 4);
  int*      vlist  = (int*)alloc((size_t)NNODES * MAXVDEG * 4);
  double*   nobuf  = (double*)alloc(2 * 8);
  (void)ws_size; (void)n_in; (void)out_size;

  int packItems  = MM * 16 + ncw * 16;
  int packBlocks = (packItems + 511) / 512;
  int bfBlocks   = (ncw * KK + 511) / 512;
  int setupGrid  = 1 + packBlocks + bfBlocks;

  k_setup<<<dim3(setupGrid), dim3(512), 0, stream>>>(cn, vn, E, ebno, P, b, ncw,
                                                     cinfo, vlist, coff, nobuf,
                                                     Ppack, bpack, out, packBlocks);
  k_lmmse<<<dim3((T + TB - 1) / TB), dim3(TB), 0, stream>>>(h_re, h_im, nre, nim, nobuf,
                                                            bpack, Ppack, Lch2, T, ncw);
  k_bp<<<dim3(ncw / 4), dim3(TB), 0, stream>>>(Lch2, vlist, coff, cinfo, out, E, ncw);
}

// Round 11
// 195.936 us; speedup vs baseline: 1.3689x; 1.0637x over previous
//
#include <hip/hip_runtime.h>
#include <math.h>

// Problem constants (from reference)
#define KK     500   // info bits
#define MM     500   // parity checks
#define NNODES 1000  // N = K + M variable nodes
#define NSYM   250   // N / BPS
#define NITERS 5
#define MAXVDEG 4    // info vars degree exactly 3 (row weight of P), parity vars 1
#define EMAX   2048  // E = 2000 edges
#define TB     256

// ---------------- setup: graph build + bit packing + bf output -------------
__global__ void __launch_bounds__(512)
k_setup(const int* __restrict__ cn, const int* __restrict__ vn, int E,
        const float* __restrict__ ebno, const int* __restrict__ P,
        const int* __restrict__ b, int ncw,
        int* __restrict__ cinfo, int* __restrict__ vlist, int* __restrict__ coff,
        double* __restrict__ nobuf, unsigned* __restrict__ Ppack,
        unsigned* __restrict__ bpack, float* __restrict__ out, int packBlocks) {
  __shared__ int sdeg[512];
  __shared__ int ssc[512];
  __shared__ int scur[512];
  __shared__ int svc[NNODES];
  int tid = threadIdx.x;
  int bx = blockIdx.x;

  if (bx == 0) {
    sdeg[tid] = 0;
    for (int n = tid; n < NNODES; n += 512) svc[n] = 0;
    __syncthreads();
    for (int e = tid; e < E; e += 512) atomicAdd(&sdeg[cn[e]], 1);
    __syncthreads();
    int v = sdeg[tid];
    ssc[tid] = v;
    __syncthreads();
    for (int o = 1; o < 512; o <<= 1) {
      int x = (tid >= o) ? ssc[tid - o] : 0;
      __syncthreads();
      ssc[tid] += x;
      __syncthreads();
    }
    int excl = ssc[tid] - v;
    scur[tid] = excl;
    if (tid < MM) {
      coff[tid] = excl;
      if (tid == MM - 1) coff[MM] = ssc[tid];
    }
    __syncthreads();
    for (int e = tid; e < E; e += 512) {
      int c = cn[e], n = vn[e];
      int slot = atomicAdd(&scur[c], 1);
      cinfo[slot] = (c << 16) | n;
      int t = atomicAdd(&svc[n], 1);
      if (t < MAXVDEG) vlist[n * MAXVDEG + t] = slot;
    }
    if (tid == 0) {
      double no = 1.0 / (pow(10.0, (double)ebno[0] * 0.1) * 2.0);  // BPS*RATE = 2
      nobuf[0] = no;
      nobuf[1] = sqrt(no * 0.5);
    }
    return;
  }

  if (bx <= packBlocks) {
    int id = (bx - 1) * 512 + tid;
    if (id < MM * 16) {
      int j = id >> 4, w = id & 15;
      unsigned word = 0u;
      int base = w * 32;
      for (int bit = 0; bit < 32; ++bit) {
        int i = base + bit;
        if (i < KK && P[i * MM + j] != 0) word |= (1u << bit);
      }
      Ppack[j * 16 + w] = word;
    } else {
      int id2 = id - MM * 16;
      if (id2 < ncw * 16) {
        int cw = id2 >> 4, w = id2 & 15;
        unsigned word = 0u;
        int base = w * 32;
        for (int bit = 0; bit < 32; ++bit) {
          int i = base + bit;
          if (i < KK && b[cw * KK + i] != 0) word |= (1u << bit);
        }
        bpack[cw * 16 + w] = word;
      }
    }
    return;
  }

  int id = (bx - 1 - packBlocks) * 512 + tid;
  if (id < ncw * KK) out[id] = (float)b[id];
}

// ---------------- 16-QAM constellation (fp64 for TX symbol) ----------------
__device__ __forceinline__ void qam_point(int p, double& re, double& im) {
  const double s = 0.31622776601683794;  // 1/sqrt(10)
  int b0 = (p >> 3) & 1, b1 = (p >> 2) & 1, b2 = (p >> 1) & 1, b3 = p & 1;
  re = (double)((1 - 2 * b0) * (2 - (1 - 2 * b2))) * s;
  im = (double)((1 - 2 * b1) * (2 - (1 - 2 * b3))) * s;
}

// ---------------- channel + LMMSE + max-log LLR --------------------------
// Symbols computed inline from bpack/Ppack; fp64 channel/Cholesky/solve
// (scalarized); fp32 demap.  Output layout Lch3[bt][plane][node][2]
// (plane 0 = ue{0,1}, plane 1 = ue{2,3}) for the 2-codeword-pair BP kernel.
__global__ void __launch_bounds__(256, 1)
k_lmmse(const float* __restrict__ h_re, const float* __restrict__ h_im,
        const float* __restrict__ n_re, const float* __restrict__ n_im,
        const double* __restrict__ nobuf,
        const unsigned* __restrict__ bpack, const unsigned* __restrict__ Ppack,
        float* __restrict__ Lch3, int T, int ncw) {
  int t = blockIdx.x * blockDim.x + threadIdx.x;
  if (t >= T) return;
  int bt = t / NSYM, s = t - bt * NSYM;

  double no = nobuf[0];
  double sq = nobuf[1];
  const double is2 = 0.7071067811865475244;  // 1/sqrt(2)

  double Hr[4][4], Hi[4][4];
  {
    const float4* hr4 = (const float4*)h_re;
    const float4* hi4 = (const float4*)h_im;
    #pragma unroll
    for (int i = 0; i < 4; ++i) {
      float4 a = hr4[t * 4 + i], c = hi4[t * 4 + i];
      Hr[i][0] = (double)a.x * is2; Hr[i][1] = (double)a.y * is2;
      Hr[i][2] = (double)a.z * is2; Hr[i][3] = (double)a.w * is2;
      Hi[i][0] = (double)c.x * is2; Hi[i][1] = (double)c.y * is2;
      Hi[i][2] = (double)c.z * is2; Hi[i][3] = (double)c.w * is2;
    }
  }

  // transmitted symbols: encode+map inline
  double xr[4], xi[4];
  #pragma unroll
  for (int ue = 0; ue < 4; ++ue) {
    const unsigned* bp = bpack + (bt * 4 + ue) * 16;
    int v = 0;
    #pragma unroll
    for (int k = 0; k < 4; ++k) {
      int n = 4 * s + k;
      int bit;
      if (n < KK) {
        bit = (bp[n >> 5] >> (n & 31)) & 1;
      } else {
        const unsigned* pp = Ppack + (n - KK) * 16;
        int cnt = 0;
        #pragma unroll
        for (int w = 0; w < 16; ++w) cnt += __popc(bp[w] & pp[w]);
        bit = cnt & 1;
      }
      v = (v << 1) | bit;  // MSB-first: weights 8,4,2,1
    }
    qam_point(v, xr[ue], xi[ue]);
  }

  // y = H x + w
  double yr[4], yi[4];
  {
    float4 wr = ((const float4*)n_re)[t];
    float4 wi = ((const float4*)n_im)[t];
    float wrv[4] = {wr.x, wr.y, wr.z, wr.w};
    float wiv[4] = {wi.x, wi.y, wi.z, wi.w};
    #pragma unroll
    for (int i = 0; i < 4; ++i) {
      double ar = (double)wrv[i] * sq;
      double ai = (double)wiv[i] * sq;
      #pragma unroll
      for (int j = 0; j < 4; ++j) {
        ar += Hr[i][j] * xr[j] - Hi[i][j] * xi[j];
        ai += Hr[i][j] * xi[j] + Hi[i][j] * xr[j];
      }
      yr[i] = ar; yi[i] = ai;
    }
  }

  // A = H H^H + no I, lower triangle, into scalars
  auto dotc = [&](int i, int j, double& ar, double& ai) {
    double r = 0.0, m = 0.0;
    #pragma unroll
    for (int k = 0; k < 4; ++k) {
      r += Hr[i][k] * Hr[j][k] + Hi[i][k] * Hi[j][k];
      m += Hi[i][k] * Hr[j][k] - Hr[i][k] * Hi[j][k];
    }
    ar = r; ai = m;
  };
  double a00, a11, a22, a33, dum;
  double a10r, a10i, a20r, a20i, a21r, a21i, a30r, a30i, a31r, a31i, a32r, a32i;
  dotc(0, 0, a00, dum);  a00 += no;
  dotc(1, 0, a10r, a10i);
  dotc(1, 1, a11, dum);  a11 += no;
  dotc(2, 0, a20r, a20i);
  dotc(2, 1, a21r, a21i);
  dotc(2, 2, a22, dum);  a22 += no;
  dotc(3, 0, a30r, a30i);
  dotc(3, 1, a31r, a31i);
  dotc(3, 2, a32r, a32i);
  dotc(3, 3, a33, dum);  a33 += no;

  // Cholesky A = L L^H (scalarized)
  double L00 = sqrt(a00);
  double i00 = 1.0 / L00;
  double L10r = a10r * i00, L10i = a10i * i00;
  double L20r = a20r * i00, L20i = a20i * i00;
  double L30r = a30r * i00, L30i = a30i * i00;
  double L11 = sqrt(a11 - (L10r * L10r + L10i * L10i));
  double i11 = 1.0 / L11;
  double L21r = (a21r - (L20r * L10r + L20i * L10i)) * i11;
  double L21i = (a21i - (L20i * L10r - L20r * L10i)) * i11;
  double L31r = (a31r - (L30r * L10r + L30i * L10i)) * i11;
  double L31i = (a31i - (L30i * L10r - L30r * L10i)) * i11;
  double L22 = sqrt(a22 - (L20r * L20r + L20i * L20i) - (L21r * L21r + L21i * L21i));
  double i22 = 1.0 / L22;
  double L32r = (a32r - (L30r * L20r + L30i * L20i) - (L31r * L21r + L31i * L21i)) * i22;
  double L32i = (a32i - (L30i * L20r - L30r * L20i) - (L31i * L21r - L31r * L21i)) * i22;
  double L33 = sqrt(a33 - (L30r * L30r + L30i * L30i) - (L31r * L31r + L31i * L31i)
                        - (L32r * L32r + L32i * L32i));
  double i33 = 1.0 / L33;

  // forward solve: U = L^{-1} H (in place on H), v = L^{-1} y (in place on y)
  #pragma unroll
  for (int j = 0; j < 4; ++j) {
    double u0r = Hr[0][j] * i00,               u0i = Hi[0][j] * i00;
    double u1r = (Hr[1][j] - (L10r * u0r - L10i * u0i)) * i11;
    double u1i = (Hi[1][j] - (L10r * u0i + L10i * u0r)) * i11;
    double u2r = (Hr[2][j] - (L20r * u0r - L20i * u0i) - (L21r * u1r - L21i * u1i)) * i22;
    double u2i = (Hi[2][j] - (L20r * u0i + L20i * u0r) - (L21r * u1i + L21i * u1r)) * i22;
    double u3r = (Hr[3][j] - (L30r * u0r - L30i * u0i) - (L31r * u1r - L31i * u1i)
                           - (L32r * u2r - L32i * u2i)) * i33;
    double u3i = (Hi[3][j] - (L30r * u0i + L30i * u0r) - (L31r * u1i + L31i * u1r)
                           - (L32r * u2i + L32i * u2r)) * i33;
    Hr[0][j] = u0r; Hi[0][j] = u0i; Hr[1][j] = u1r; Hi[1][j] = u1i;
    Hr[2][j] = u2r; Hi[2][j] = u2i; Hr[3][j] = u3r; Hi[3][j] = u3i;
  }
  {
    double v0r = yr[0] * i00,               v0i = yi[0] * i00;
    double v1r = (yr[1] - (L10r * v0r - L10i * v0i)) * i11;
    double v1i = (yi[1] - (L10r * v0i + L10i * v0r)) * i11;
    double v2r = (yr[2] - (L20r * v0r - L20i * v0i) - (L21r * v1r - L21i * v1i)) * i22;
    double v2i = (yi[2] - (L20r * v0i + L20i * v0r) - (L21r * v1i + L21i * v1r)) * i22;
    double v3r = (yr[3] - (L30r * v0r - L30i * v0i) - (L31r * v1r - L31i * v1i)
                        - (L32r * v2r - L32i * v2i)) * i33;
    double v3i = (yi[3] - (L30r * v0i + L30i * v0r) - (L31r * v1i + L31i * v1r)
                        - (L32r * v2i + L32i * v2r)) * i33;
    yr[0] = v0r; yi[0] = v0i; yr[1] = v1r; yi[1] = v1i;
    yr[2] = v2r; yi[2] = v2i; yr[3] = v3r; yi[3] = v3i;
  }

  // fp32 16-QAM table
  const float PRT[16] = { 0.31622776601683794f, 0.31622776601683794f, 0.9486832980505138f, 0.9486832980505138f,
                          0.31622776601683794f, 0.31622776601683794f, 0.9486832980505138f, 0.9486832980505138f,
                         -0.31622776601683794f,-0.31622776601683794f,-0.9486832980505138f,-0.9486832980505138f,
                         -0.31622776601683794f,-0.31622776601683794f,-0.9486832980505138f,-0.9486832980505138f };
  const float PIT[16] = { 0.31622776601683794f, 0.9486832980505138f, 0.31622776601683794f, 0.9486832980505138f,
                         -0.31622776601683794f,-0.9486832980505138f,-0.31622776601683794f,-0.9486832980505138f,
                          0.31622776601683794f, 0.9486832980505138f, 0.31622776601683794f, 0.9486832980505138f,
                         -0.31622776601683794f,-0.9486832980505138f,-0.31622776601683794f,-0.9486832980505138f };

  float llr[4][4];  // [bit k][ue j]
  #pragma unroll
  for (int j = 0; j < 4; ++j) {
    double dj = 0.0, rr = 0.0, ri = 0.0;
    #pragma unroll
    for (int i = 0; i < 4; ++i) {
      dj += Hr[i][j] * Hr[i][j] + Hi[i][j] * Hi[i][j];
      rr += Hr[i][j] * yr[i] + Hi[i][j] * yi[i];
      ri += Hr[i][j] * yi[i] - Hi[i][j] * yr[i];
    }
    float xhr = (float)(rr / dj), xhi = (float)(ri / dj);
    float inoe = (float)(1.0 / fmax(1.0 / dj - 1.0, 1e-12));

    float m0[4] = {-1e30f, -1e30f, -1e30f, -1e30f};
    float m1[4] = {-1e30f, -1e30f, -1e30f, -1e30f};
    #pragma unroll
    for (int p = 0; p < 16; ++p) {
      float dr = xhr - PRT[p], di = xhi - PIT[p];
      float met = -(dr * dr + di * di) * inoe;
      #pragma unroll
      for (int k = 0; k < 4; ++k) {
        if ((p >> (3 - k)) & 1) m1[k] = fmaxf(m1[k], met);
        else                    m0[k] = fmaxf(m0[k], met);
      }
    }
    #pragma unroll
    for (int k = 0; k < 4; ++k) llr[k][j] = m0[k] - m1[k];
  }

  // store: plane 0 = ue{0,1}, plane 1 = ue{2,3}
  float2* pl0 = (float2*)(Lch3 + (size_t)bt * (NNODES * 4));
  float2* pl1 = pl0 + NNODES;
  #pragma unroll
  for (int k = 0; k < 4; ++k) {
    int node = 4 * s + k;
    pl0[node] = make_float2(llr[k][0], llr[k][1]);
    pl1[node] = make_float2(llr[k][2], llr[k][3]);
  }
}

// ---------------- fused LDS-resident BP decoder, 2 codewords / block --------
// w-domain with the (A-B)/(A+B) substitution:
//   t_new = (A-B)/(A+B),  A = E*a_sib1*a_sib2,  B = b_sib1*b_sib2,
//   a = 1+r, b = 1-r, r = clip(P/t, +-0.999999), E = exp(clip(L,+-55)).
// Identical to W=(1+r)/(1-r), w=E*W*W, t=(w-1)/(w+1) (rounds differently by
// ~ulp only).  The old w-clamp [e^-19.8, e^19.8] is dropped: its clip region
// collapses to t = +-1.0f in fp32 (tanh(9.9) rounds to 1.0f), which
// (A-B)/(A+B) already saturates to.  NaN impossible: A >= E*1e-12 > 0,
// B >= 1e-12.  1e-7 magnitude floor retained.
// Channel L kept in REGISTERS (only the owning thread reads it) -> no sL:
// LDS = sT(16K) + sP(4K) = 20.5 KB -> 8 blocks/CU = 32 waves (occupancy cap).
__device__ __forceinline__ float tanh_half(float m) {
  float mc = fminf(fmaxf(m, -19.8f), 19.8f);
  float e = __expf(mc);
  float t = 1.0f - __fdividef(2.0f, e + 1.0f);
  return (t >= 0.0f) ? fmaxf(t, 1e-7f) : fminf(t, -1e-7f);
}
__device__ __forceinline__ float rclip(float P, float t) {
  float r = __fdividef(P, t);
  return fminf(fmaxf(r, -0.999999f), 0.999999f);
}
__device__ __forceinline__ float tfloor(float t) {
  return (t >= 0.0f) ? fmaxf(t, 1e-7f) : fminf(t, -1e-7f);
}
__device__ __forceinline__ float atanh2c(float P, float t) {
  float r = __fdividef(P, t);
  r = fminf(fmaxf(r, -0.999999f), 0.999999f);
  return __logf(__fdividef(1.0f + r, 1.0f - r));
}

__global__ void __launch_bounds__(256) k_bp(const float* __restrict__ Lch3,
                                            const int* __restrict__ vlist,
                                            const int* __restrict__ coff,
                                            const int* __restrict__ cinfo,
                                            float* __restrict__ out, int E, int ncw) {
  __shared__ float2 sT[EMAX];   // tanh(v2c/2) per edge slot (16 KB)
  __shared__ float2 sP[512];    // per-check product of tanh (4 KB)

  int tid = threadIdx.x;
  int pairId = blockIdx.x;  // = bt*2 + plane; codewords 2*pairId, 2*pairId+1

  const float2* src = (const float2*)(Lch3 + (size_t)pairId * (NNODES * 2));

  // own info-node state in registers; parity tanh straight into sT
  float2 Ln[2], En[2];
  int pk0[2], pk1[2], pk2[2]; bool iok[2];
  #pragma unroll
  for (int i = 0; i < 2; ++i) {
    int n = tid + TB * i;
    iok[i] = n < KK;
    Ln[i] = make_float2(0.f, 0.f);
    En[i] = make_float2(1.f, 1.f);
    pk0[i] = pk1[i] = pk2[i] = 0;
    if (iok[i]) {
      float2 L = src[n];
      Ln[i] = L;
      En[i] = make_float2(__expf(fminf(fmaxf(L.x, -55.f), 55.f)),
                          __expf(fminf(fmaxf(L.y, -55.f), 55.f)));
      int s0 = vlist[n * MAXVDEG], s1 = vlist[n * MAXVDEG + 1], s2 = vlist[n * MAXVDEG + 2];
      pk0[i] = (cinfo[s0] & 0xffff0000) | s0;
      pk1[i] = (cinfo[s1] & 0xffff0000) | s1;
      pk2[i] = (cinfo[s2] & 0xffff0000) | s2;
    }
  }
  #pragma unroll
  for (int i = 0; i < 2; ++i) {
    int n = KK + tid + TB * i;
    if (n < NNODES) {
      int slot = vlist[n * MAXVDEG];
      float2 L = src[n];
      sT[slot] = make_float2(tanh_half(L.x), tanh_half(L.y));
    }
  }
  int beg0 = coff[tid], end0 = coff[tid + 1];
  bool c1ok = (tid + TB) < MM;
  int beg1 = c1ok ? coff[tid + TB] : 0;
  int end1 = c1ok ? coff[tid + TB + 1] : 0;
  // no barrier needed: first sT reads happen in pass 2, after the in-loop barrier

  for (int it = 0; it < NITERS; ++it) {
    // ---- pass 1: info-node var update ----
    if (it == 0) {
      #pragma unroll
      for (int i = 0; i < 2; ++i) {
        if (iok[i]) {
          float2 t = make_float2(tanh_half(Ln[i].x), tanh_half(Ln[i].y));
          sT[pk0[i] & 0xffff] = t;
          sT[pk1[i] & 0xffff] = t;
          sT[pk2[i] & 0xffff] = t;
        }
      }
    } else {
      #pragma unroll
      for (int i = 0; i < 2; ++i) {
        if (iok[i]) {
          int s0 = pk0[i] & 0xffff, c0 = ((unsigned)pk0[i]) >> 16;
          int s1 = pk1[i] & 0xffff, c1 = ((unsigned)pk1[i]) >> 16;
          int s2 = pk2[i] & 0xffff, c2 = ((unsigned)pk2[i]) >> 16;
          float2 P0 = sP[c0], P1 = sP[c1], P2 = sP[c2];
          float2 t0 = sT[s0], t1 = sT[s1], t2 = sT[s2];
          // lane x
          float r0 = rclip(P0.x, t0.x), r1 = rclip(P1.x, t1.x), r2 = rclip(P2.x, t2.x);
          float a0 = 1.f + r0, a1 = 1.f + r1, a2 = 1.f + r2;
          float b0 = 1.f - r0, b1 = 1.f - r1, b2 = 1.f - r2;
          float Ex = En[i].x;
          float A0 = Ex * (a1 * a2), A1 = Ex * (a0 * a2), A2 = Ex * (a0 * a1);
          float B0 = b1 * b2,        B1 = b0 * b2,        B2 = b0 * b1;
          float n0x = tfloor(__fdividef(A0 - B0, A0 + B0));
          float n1x = tfloor(__fdividef(A1 - B1, A1 + B1));
          float n2x = tfloor(__fdividef(A2 - B2, A2 + B2));
          // lane y
          float q0 = rclip(P0.y, t0.y), q1 = rclip(P1.y, t1.y), q2 = rclip(P2.y, t2.y);
          float c0a = 1.f + q0, c1a = 1.f + q1, c2a = 1.f + q2;
          float d0b = 1.f - q0, d1b = 1.f - q1, d2b = 1.f - q2;
          float Ey = En[i].y;
          float C0 = Ey * (c1a * c2a), C1 = Ey * (c0a * c2a), C2 = Ey * (c0a * c1a);
          float D0 = d1b * d2b,        D1 = d0b * d2b,        D2 = d0b * d1b;
          float n0y = tfloor(__fdividef(C0 - D0, C0 + D0));
          float n1y = tfloor(__fdividef(C1 - D1, C1 + D1));
          float n2y = tfloor(__fdividef(C2 - D2, C2 + D2));
          sT[s0] = make_float2(n0x, n0y);
          sT[s1] = make_float2(n1x, n1y);
          sT[s2] = make_float2(n2x, n2y);
        }
      }
    }
    __syncthreads();
    // ---- pass 2: per-check products ----
    {
      float px = 1.0f, py = 1.0f;
      for (int e = beg0; e < end0; ++e) { float2 tt = sT[e]; px *= tt.x; py *= tt.y; }
      sP[tid] = make_float2(px, py);
      if (c1ok) {
        float qx = 1.0f, qy = 1.0f;
        for (int e = beg1; e < end1; ++e) { float2 tt = sT[e]; qx *= tt.x; qy *= tt.y; }
        sP[tid + TB] = make_float2(qx, qy);
      }
    }
    __syncthreads();
  }

  // ---- decide: additive log form (once) ----
  int cw0 = pairId * 2;
  float* o0 = out + (size_t)ncw * KK + (size_t)cw0 * KK;
  float* o1 = o0 + KK;
  #pragma unroll
  for (int i = 0; i < 2; ++i) {
    if (iok[i]) {
      int n = tid + TB * i;
      int s0 = pk0[i] & 0xffff, c0 = ((unsigned)pk0[i]) >> 16;
      int s1 = pk1[i] & 0xffff, c1 = ((unsigned)pk1[i]) >> 16;
      int s2 = pk2[i] & 0xffff, c2 = ((unsigned)pk2[i]) >> 16;
      float2 P0 = sP[c0], P1 = sP[c1], P2 = sP[c2];
      float2 t0 = sT[s0], t1 = sT[s1], t2 = sT[s2];
      float2 L = Ln[i];
      float ax = L.x + atanh2c(P0.x, t0.x) + atanh2c(P1.x, t1.x) + atanh2c(P2.x, t2.x);
      float ay = L.y + atanh2c(P0.y, t0.y) + atanh2c(P1.y, t1.y) + atanh2c(P2.y, t2.y);
      o0[n] = (ax < 0.0f) ? 1.0f : 0.0f;
      o1[n] = (ay < 0.0f) ? 1.0f : 0.0f;
    }
  }
}

// ---------------- launcher ----------------
extern "C" void kernel_launch(void* const* d_in, const int* in_sizes, int n_in,
                              void* d_out, int out_size, void* d_ws, size_t ws_size,
                              hipStream_t stream) {
  const float* ebno = (const float*)d_in[1];
  const int*   b    = (const int*)d_in[2];
  const int*   P    = (const int*)d_in[3];
  const int*   cn   = (const int*)d_in[4];
  const int*   vn   = (const int*)d_in[5];
  const float* h_re = (const float*)d_in[6];
  const float* h_im = (const float*)d_in[7];
  const float* nre  = (const float*)d_in[8];
  const float* nim  = (const float*)d_in[9];
  float* out = (float*)d_out;

  int E     = in_sizes[4];
  int batch = in_sizes[2] / (4 * KK);
  int ncw   = batch * 4;
  int T     = batch * NSYM;

  char* ws = (char*)d_ws;
  size_t off = 0;
  auto alloc = [&](size_t bytes) -> void* {
    void* p = ws + off;
    off += (bytes + 255) & ~(size_t)255;
    return p;
  };
  float*    Lch3   = (float*)alloc((size_t)NNODES * ncw * 4);
  unsigned* Ppack  = (unsigned*)alloc((size_t)MM * 16 * 4);
  unsigned* bpack  = (unsigned*)alloc((size_t)ncw * 16 * 4);
  int*      coff   = (int*)alloc((size_t)(MM + 1) * 4);
  int*      cinfo  = (int*)alloc((size_t)EMAX * 4);
  int*      vlist  = (int*)alloc((size_t)NNODES * MAXVDEG * 4);
  double*   nobuf  = (double*)alloc(2 * 8);
  (void)ws_size; (void)n_in; (void)out_size;

  int packItems  = MM * 16 + ncw * 16;
  int packBlocks = (packItems + 511) / 512;
  int bfBlocks   = (ncw * KK + 511) / 512;
  int setupGrid  = 1 + packBlocks + bfBlocks;

  k_setup<<<dim3(setupGrid), dim3(512), 0, stream>>>(cn, vn, E, ebno, P, b, ncw,
                                                     cinfo, vlist, coff, nobuf,
                                                     Ppack, bpack, out, packBlocks);
  k_lmmse<<<dim3((T + TB - 1) / TB), dim3(TB), 0, stream>>>(h_re, h_im, nre, nim, nobuf,
                                                            bpack, Ppack, Lch3, T, ncw);
  k_bp<<<dim3(ncw / 2), dim3(TB), 0, stream>>>(Lch3, vlist, coff, cinfo, out, E, ncw);
}

// Round 12
// 186.922 us; speedup vs baseline: 1.4349x; 1.0482x over previous
//
#include <hip/hip_runtime.h>
#include <math.h>

// Problem constants (from reference)
#define KK     500   // info bits
#define MM     500   // parity checks
#define NNODES 1000  // N = K + M variable nodes
#define NSYM   250   // N / BPS
#define NITERS 5
#define MAXVDEG 4    // info vars degree exactly 3 (row weight of P), parity vars 1
#define EMAX   2048  // E = 2000 edges
#define TB     256

// ---------------- setup: graph build + bit packing + bf output -------------
// Slot layout per check c: info edges in coff[c]..coff[c+1]-2 (atomic order),
// the single parity edge (var >= KK) pinned to coff[c+1]-1 so the BP product
// loop can skip it and use a register-cached constant instead.
__global__ void __launch_bounds__(512)
k_setup(const int* __restrict__ cn, const int* __restrict__ vn, int E,
        const float* __restrict__ ebno, const int* __restrict__ P,
        const int* __restrict__ b, int ncw,
        int* __restrict__ cinfo, int* __restrict__ vlist, int* __restrict__ coff,
        double* __restrict__ nobuf, unsigned* __restrict__ Ppack,
        unsigned* __restrict__ bpack, float* __restrict__ out, int packBlocks) {
  __shared__ int sdeg[512];
  __shared__ int ssc[512];
  __shared__ int scur[512];
  __shared__ int svc[NNODES];
  int tid = threadIdx.x;
  int bx = blockIdx.x;

  if (bx == 0) {
    sdeg[tid] = 0;
    for (int n = tid; n < NNODES; n += 512) svc[n] = 0;
    __syncthreads();
    for (int e = tid; e < E; e += 512) atomicAdd(&sdeg[cn[e]], 1);
    __syncthreads();
    int v = sdeg[tid];
    ssc[tid] = v;
    __syncthreads();
    for (int o = 1; o < 512; o <<= 1) {
      int x = (tid >= o) ? ssc[tid - o] : 0;
      __syncthreads();
      ssc[tid] += x;
      __syncthreads();
    }
    int excl = ssc[tid] - v;
    scur[tid] = excl;
    if (tid < MM) {
      coff[tid] = excl;
      if (tid == MM - 1) coff[MM] = ssc[tid];
    }
    __syncthreads();
    for (int e = tid; e < E; e += 512) {
      int c = cn[e], n = vn[e];
      int slot;
      if (n >= KK) {
        slot = ssc[c] - 1;               // parity edge -> last slot of check c
      } else {
        slot = atomicAdd(&scur[c], 1);   // info edges fill coff[c]..coff[c+1]-2
      }
      cinfo[slot] = (c << 16) | n;
      if (n < KK) {
        int t = atomicAdd(&svc[n], 1);
        if (t < MAXVDEG) vlist[n * MAXVDEG + t] = slot;
      }
    }
    if (tid == 0) {
      double no = 1.0 / (pow(10.0, (double)ebno[0] * 0.1) * 2.0);  // BPS*RATE = 2
      nobuf[0] = no;
      nobuf[1] = sqrt(no * 0.5);
    }
    return;
  }

  if (bx <= packBlocks) {
    int id = (bx - 1) * 512 + tid;
    if (id < MM * 16) {
      int j = id >> 4, w = id & 15;
      unsigned word = 0u;
      int base = w * 32;
      for (int bit = 0; bit < 32; ++bit) {
        int i = base + bit;
        if (i < KK && P[i * MM + j] != 0) word |= (1u << bit);
      }
      Ppack[j * 16 + w] = word;
    } else {
      int id2 = id - MM * 16;
      if (id2 < ncw * 16) {
        int cw = id2 >> 4, w = id2 & 15;
        unsigned word = 0u;
        int base = w * 32;
        for (int bit = 0; bit < 32; ++bit) {
          int i = base + bit;
          if (i < KK && b[cw * KK + i] != 0) word |= (1u << bit);
        }
        bpack[cw * 16 + w] = word;
      }
    }
    return;
  }

  int id = (bx - 1 - packBlocks) * 512 + tid;
  if (id < ncw * KK) out[id] = (float)b[id];
}

// ---------------- 16-QAM constellation (fp64 for TX symbol) ----------------
__device__ __forceinline__ void qam_point(int p, double& re, double& im) {
  const double s = 0.31622776601683794;  // 1/sqrt(10)
  int b0 = (p >> 3) & 1, b1 = (p >> 2) & 1, b2 = (p >> 1) & 1, b3 = p & 1;
  re = (double)((1 - 2 * b0) * (2 - (1 - 2 * b2))) * s;
  im = (double)((1 - 2 * b1) * (2 - (1 - 2 * b3))) * s;
}

// ---------------- channel + LMMSE + max-log LLR --------------------------
// Symbols computed inline from bpack/Ppack; fp64 channel/Cholesky/solve
// (scalarized); fp32 demap.  Output layout Lch3[bt][plane][node][2]
// (plane 0 = ue{0,1}, plane 1 = ue{2,3}) for the 2-codeword-pair BP kernel.
__global__ void __launch_bounds__(256, 1)
k_lmmse(const float* __restrict__ h_re, const float* __restrict__ h_im,
        const float* __restrict__ n_re, const float* __restrict__ n_im,
        const double* __restrict__ nobuf,
        const unsigned* __restrict__ bpack, const unsigned* __restrict__ Ppack,
        float* __restrict__ Lch3, int T, int ncw) {
  int t = blockIdx.x * blockDim.x + threadIdx.x;
  if (t >= T) return;
  int bt = t / NSYM, s = t - bt * NSYM;

  double no = nobuf[0];
  double sq = nobuf[1];
  const double is2 = 0.7071067811865475244;  // 1/sqrt(2)

  double Hr[4][4], Hi[4][4];
  {
    const float4* hr4 = (const float4*)h_re;
    const float4* hi4 = (const float4*)h_im;
    #pragma unroll
    for (int i = 0; i < 4; ++i) {
      float4 a = hr4[t * 4 + i], c = hi4[t * 4 + i];
      Hr[i][0] = (double)a.x * is2; Hr[i][1] = (double)a.y * is2;
      Hr[i][2] = (double)a.z * is2; Hr[i][3] = (double)a.w * is2;
      Hi[i][0] = (double)c.x * is2; Hi[i][1] = (double)c.y * is2;
      Hi[i][2] = (double)c.z * is2; Hi[i][3] = (double)c.w * is2;
    }
  }

  // transmitted symbols: encode+map inline
  double xr[4], xi[4];
  #pragma unroll
  for (int ue = 0; ue < 4; ++ue) {
    const unsigned* bp = bpack + (bt * 4 + ue) * 16;
    int v = 0;
    #pragma unroll
    for (int k = 0; k < 4; ++k) {
      int n = 4 * s + k;
      int bit;
      if (n < KK) {
        bit = (bp[n >> 5] >> (n & 31)) & 1;
      } else {
        const unsigned* pp = Ppack + (n - KK) * 16;
        int cnt = 0;
        #pragma unroll
        for (int w = 0; w < 16; ++w) cnt += __popc(bp[w] & pp[w]);
        bit = cnt & 1;
      }
      v = (v << 1) | bit;  // MSB-first: weights 8,4,2,1
    }
    qam_point(v, xr[ue], xi[ue]);
  }

  // y = H x + w
  double yr[4], yi[4];
  {
    float4 wr = ((const float4*)n_re)[t];
    float4 wi = ((const float4*)n_im)[t];
    float wrv[4] = {wr.x, wr.y, wr.z, wr.w};
    float wiv[4] = {wi.x, wi.y, wi.z, wi.w};
    #pragma unroll
    for (int i = 0; i < 4; ++i) {
      double ar = (double)wrv[i] * sq;
      double ai = (double)wiv[i] * sq;
      #pragma unroll
      for (int j = 0; j < 4; ++j) {
        ar += Hr[i][j] * xr[j] - Hi[i][j] * xi[j];
        ai += Hr[i][j] * xi[j] + Hi[i][j] * xr[j];
      }
      yr[i] = ar; yi[i] = ai;
    }
  }

  // A = H H^H + no I, lower triangle, into scalars
  auto dotc = [&](int i, int j, double& ar, double& ai) {
    double r = 0.0, m = 0.0;
    #pragma unroll
    for (int k = 0; k < 4; ++k) {
      r += Hr[i][k] * Hr[j][k] + Hi[i][k] * Hi[j][k];
      m += Hi[i][k] * Hr[j][k] - Hr[i][k] * Hi[j][k];
    }
    ar = r; ai = m;
  };
  double a00, a11, a22, a33, dum;
  double a10r, a10i, a20r, a20i, a21r, a21i, a30r, a30i, a31r, a31i, a32r, a32i;
  dotc(0, 0, a00, dum);  a00 += no;
  dotc(1, 0, a10r, a10i);
  dotc(1, 1, a11, dum);  a11 += no;
  dotc(2, 0, a20r, a20i);
  dotc(2, 1, a21r, a21i);
  dotc(2, 2, a22, dum);  a22 += no;
  dotc(3, 0, a30r, a30i);
  dotc(3, 1, a31r, a31i);
  dotc(3, 2, a32r, a32i);
  dotc(3, 3, a33, dum);  a33 += no;

  // Cholesky A = L L^H (scalarized)
  double L00 = sqrt(a00);
  double i00 = 1.0 / L00;
  double L10r = a10r * i00, L10i = a10i * i00;
  double L20r = a20r * i00, L20i = a20i * i00;
  double L30r = a30r * i00, L30i = a30i * i00;
  double L11 = sqrt(a11 - (L10r * L10r + L10i * L10i));
  double i11 = 1.0 / L11;
  double L21r = (a21r - (L20r * L10r + L20i * L10i)) * i11;
  double L21i = (a21i - (L20i * L10r - L20r * L10i)) * i11;
  double L31r = (a31r - (L30r * L10r + L30i * L10i)) * i11;
  double L31i = (a31i - (L30i * L10r - L30r * L10i)) * i11;
  double L22 = sqrt(a22 - (L20r * L20r + L20i * L20i) - (L21r * L21r + L21i * L21i));
  double i22 = 1.0 / L22;
  double L32r = (a32r - (L30r * L20r + L30i * L20i) - (L31r * L21r + L31i * L21i)) * i22;
  double L32i = (a32i - (L30i * L20r - L30r * L20i) - (L31i * L21r - L31r * L21i)) * i22;
  double L33 = sqrt(a33 - (L30r * L30r + L30i * L30i) - (L31r * L31r + L31i * L31i)
                        - (L32r * L32r + L32i * L32i));
  double i33 = 1.0 / L33;

  // forward solve: U = L^{-1} H (in place on H), v = L^{-1} y (in place on y)
  #pragma unroll
  for (int j = 0; j < 4; ++j) {
    double u0r = Hr[0][j] * i00,               u0i = Hi[0][j] * i00;
    double u1r = (Hr[1][j] - (L10r * u0r - L10i * u0i)) * i11;
    double u1i = (Hi[1][j] - (L10r * u0i + L10i * u0r)) * i11;
    double u2r = (Hr[2][j] - (L20r * u0r - L20i * u0i) - (L21r * u1r - L21i * u1i)) * i22;
    double u2i = (Hi[2][j] - (L20r * u0i + L20i * u0r) - (L21r * u1i + L21i * u1r)) * i22;
    double u3r = (Hr[3][j] - (L30r * u0r - L30i * u0i) - (L31r * u1r - L31i * u1i)
                           - (L32r * u2r - L32i * u2i)) * i33;
    double u3i = (Hi[3][j] - (L30r * u0i + L30i * u0r) - (L31r * u1i + L31i * u1r)
                           - (L32r * u2i + L32i * u2r)) * i33;
    Hr[0][j] = u0r; Hi[0][j] = u0i; Hr[1][j] = u1r; Hi[1][j] = u1i;
    Hr[2][j] = u2r; Hi[2][j] = u2i; Hr[3][j] = u3r; Hi[3][j] = u3i;
  }
  {
    double v0r = yr[0] * i00,               v0i = yi[0] * i00;
    double v1r = (yr[1] - (L10r * v0r - L10i * v0i)) * i11;
    double v1i = (yi[1] - (L10r * v0i + L10i * v0r)) * i11;
    double v2r = (yr[2] - (L20r * v0r - L20i * v0i) - (L21r * v1r - L21i * v1i)) * i22;
    double v2i = (yi[2] - (L20r * v0i + L20i * v0r) - (L21r * v1i + L21i * v1r)) * i22;
    double v3r = (yr[3] - (L30r * v0r - L30i * v0i) - (L31r * v1r - L31i * v1i)
                        - (L32r * v2r - L32i * v2i)) * i33;
    double v3i = (yi[3] - (L30r * v0i + L30i * v0r) - (L31r * v1i + L31i * v1r)
                        - (L32r * v2i + L32i * v2r)) * i33;
    yr[0] = v0r; yi[0] = v0i; yr[1] = v1r; yi[1] = v1i;
    yr[2] = v2r; yi[2] = v2i; yr[3] = v3r; yi[3] = v3i;
  }

  // fp32 16-QAM table
  const float PRT[16] = { 0.31622776601683794f, 0.31622776601683794f, 0.9486832980505138f, 0.9486832980505138f,
                          0.31622776601683794f, 0.31622776601683794f, 0.9486832980505138f, 0.9486832980505138f,
                         -0.31622776601683794f,-0.31622776601683794f,-0.9486832980505138f,-0.9486832980505138f,
                         -0.31622776601683794f,-0.31622776601683794f,-0.9486832980505138f,-0.9486832980505138f };
  const float PIT[16] = { 0.31622776601683794f, 0.9486832980505138f, 0.31622776601683794f, 0.9486832980505138f,
                         -0.31622776601683794f,-0.9486832980505138f,-0.31622776601683794f,-0.9486832980505138f,
                          0.31622776601683794f, 0.9486832980505138f, 0.31622776601683794f, 0.9486832980505138f,
                         -0.31622776601683794f,-0.9486832980505138f,-0.31622776601683794f,-0.9486832980505138f };

  float llr[4][4];  // [bit k][ue j]
  #pragma unroll
  for (int j = 0; j < 4; ++j) {
    double dj = 0.0, rr = 0.0, ri = 0.0;
    #pragma unroll
    for (int i = 0; i < 4; ++i) {
      dj += Hr[i][j] * Hr[i][j] + Hi[i][j] * Hi[i][j];
      rr += Hr[i][j] * yr[i] + Hi[i][j] * yi[i];
      ri += Hr[i][j] * yi[i] - Hi[i][j] * yr[i];
    }
    float xhr = (float)(rr / dj), xhi = (float)(ri / dj);
    float inoe = (float)(1.0 / fmax(1.0 / dj - 1.0, 1e-12));

    float m0[4] = {-1e30f, -1e30f, -1e30f, -1e30f};
    float m1[4] = {-1e30f, -1e30f, -1e30f, -1e30f};
    #pragma unroll
    for (int p = 0; p < 16; ++p) {
      float dr = xhr - PRT[p], di = xhi - PIT[p];
      float met = -(dr * dr + di * di) * inoe;
      #pragma unroll
      for (int k = 0; k < 4; ++k) {
        if ((p >> (3 - k)) & 1) m1[k] = fmaxf(m1[k], met);
        else                    m0[k] = fmaxf(m0[k], met);
      }
    }
    #pragma unroll
    for (int k = 0; k < 4; ++k) llr[k][j] = m0[k] - m1[k];
  }

  // store: plane 0 = ue{0,1}, plane 1 = ue{2,3}
  float2* pl0 = (float2*)(Lch3 + (size_t)bt * (NNODES * 4));
  float2* pl1 = pl0 + NNODES;
  #pragma unroll
  for (int k = 0; k < 4; ++k) {
    int node = 4 * s + k;
    pl0[node] = make_float2(llr[k][0], llr[k][1]);
    pl1[node] = make_float2(llr[k][2], llr[k][3]);
  }
}

// ---------------- fused LDS-resident BP decoder, 2 codewords / block --------
// Division-free pass-1: (A-B)/(A+B) is invariant under any common nonzero
// scale of (A,B), so each factor pair is scaled by its own t:
//   a' = t + Pc,  b' = t - Pc,  Pc = copysign(min(|P|, 0.999999*|t|), P)
// which equals t*(1+clip(P/t)) / t*(1-clip(P/t)) without the division.
// A,B keep a common sign, so A+B never cancels; t has the 1e-7 floor.
// Parity edges (one per check, constant t) are factored out of the product:
// their tanh lives in a register (qpar), the CSR product loop runs [beg,end-1).
__device__ __forceinline__ float tanh_half(float m) {
  float mc = fminf(fmaxf(m, -19.8f), 19.8f);
  float e = __expf(mc);
  float t = 1.0f - __fdividef(2.0f, e + 1.0f);
  return (t >= 0.0f) ? fmaxf(t, 1e-7f) : fminf(t, -1e-7f);
}
__device__ __forceinline__ float pclip(float P, float t) {
  // t * clip(P/t, +-0.999999), computed without dividing
  return copysignf(fminf(fabsf(P), 0.999999f * fabsf(t)), P);
}
__device__ __forceinline__ float tfloor(float t) {
  return (t >= 0.0f) ? fmaxf(t, 1e-7f) : fminf(t, -1e-7f);
}
__device__ __forceinline__ float atanh2c(float P, float t) {
  float r = __fdividef(P, t);
  r = fminf(fmaxf(r, -0.999999f), 0.999999f);
  return __logf(__fdividef(1.0f + r, 1.0f - r));
}

__global__ void __launch_bounds__(256) k_bp(const float* __restrict__ Lch3,
                                            const int* __restrict__ vlist,
                                            const int* __restrict__ coff,
                                            const int* __restrict__ cinfo,
                                            float* __restrict__ out, int E, int ncw) {
  __shared__ float2 sT[EMAX];   // tanh(v2c/2) per info-edge slot (16 KB)
  __shared__ float2 sP[512];    // per-check product of tanh (4 KB)

  int tid = threadIdx.x;
  int pairId = blockIdx.x;  // = bt*2 + plane; codewords 2*pairId, 2*pairId+1

  const float2* src = (const float2*)(Lch3 + (size_t)pairId * (NNODES * 2));

  // own info-node state in registers
  float2 Ln[2], En[2];
  int pk0[2], pk1[2], pk2[2]; bool iok[2];
  #pragma unroll
  for (int i = 0; i < 2; ++i) {
    int n = tid + TB * i;
    iok[i] = n < KK;
    Ln[i] = make_float2(0.f, 0.f);
    En[i] = make_float2(1.f, 1.f);
    pk0[i] = pk1[i] = pk2[i] = 0;
    if (iok[i]) {
      float2 L = src[n];
      Ln[i] = L;
      En[i] = make_float2(__expf(fminf(fmaxf(L.x, -55.f), 55.f)),
                          __expf(fminf(fmaxf(L.y, -55.f), 55.f)));
      int s0 = vlist[n * MAXVDEG], s1 = vlist[n * MAXVDEG + 1], s2 = vlist[n * MAXVDEG + 2];
      pk0[i] = (cinfo[s0] & 0xffff0000) | s0;
      pk1[i] = (cinfo[s1] & 0xffff0000) | s1;
      pk2[i] = (cinfo[s2] & 0xffff0000) | s2;
    }
  }
  // per-check constant: tanh of the parity-node LLR (check c <-> parity var KK+c)
  float2 qpar0, qpar1;
  {
    float2 Lp0 = src[KK + tid];
    qpar0 = make_float2(tanh_half(Lp0.x), tanh_half(Lp0.y));
  }
  bool c1ok = (tid + TB) < MM;
  if (c1ok) {
    float2 Lp1 = src[KK + tid + TB];
    qpar1 = make_float2(tanh_half(Lp1.x), tanh_half(Lp1.y));
  } else {
    qpar1 = make_float2(1.f, 1.f);
  }
  int beg0 = coff[tid], end0 = coff[tid + 1];
  int beg1 = c1ok ? coff[tid + TB] : 0;
  int end1 = c1ok ? coff[tid + TB + 1] : 0;
  // no barrier needed: first sT reads happen in pass 2, after the in-loop barrier

  for (int it = 0; it < NITERS; ++it) {
    // ---- pass 1: info-node var update ----
    if (it == 0) {
      #pragma unroll
      for (int i = 0; i < 2; ++i) {
        if (iok[i]) {
          float2 t = make_float2(tanh_half(Ln[i].x), tanh_half(Ln[i].y));
          sT[pk0[i] & 0xffff] = t;
          sT[pk1[i] & 0xffff] = t;
          sT[pk2[i] & 0xffff] = t;
        }
      }
    } else {
      #pragma unroll
      for (int i = 0; i < 2; ++i) {
        if (iok[i]) {
          int s0 = pk0[i] & 0xffff, c0 = ((unsigned)pk0[i]) >> 16;
          int s1 = pk1[i] & 0xffff, c1 = ((unsigned)pk1[i]) >> 16;
          int s2 = pk2[i] & 0xffff, c2 = ((unsigned)pk2[i]) >> 16;
          float2 P0 = sP[c0], P1 = sP[c1], P2 = sP[c2];
          float2 t0 = sT[s0], t1 = sT[s1], t2 = sT[s2];
          // lane x
          float p0 = pclip(P0.x, t0.x), p1 = pclip(P1.x, t1.x), p2 = pclip(P2.x, t2.x);
          float a0 = t0.x + p0, a1 = t1.x + p1, a2 = t2.x + p2;
          float b0 = t0.x - p0, b1 = t1.x - p1, b2 = t2.x - p2;
          float Ex = En[i].x;
          float A0 = Ex * (a1 * a2), A1 = Ex * (a0 * a2), A2 = Ex * (a0 * a1);
          float B0 = b1 * b2,        B1 = b0 * b2,        B2 = b0 * b1;
          float n0x = tfloor(__fdividef(A0 - B0, A0 + B0));
          float n1x = tfloor(__fdividef(A1 - B1, A1 + B1));
          float n2x = tfloor(__fdividef(A2 - B2, A2 + B2));
          // lane y
          float q0 = pclip(P0.y, t0.y), q1 = pclip(P1.y, t1.y), q2 = pclip(P2.y, t2.y);
          float c0a = t0.y + q0, c1a = t1.y + q1, c2a = t2.y + q2;
          float d0b = t0.y - q0, d1b = t1.y - q1, d2b = t2.y - q2;
          float Ey = En[i].y;
          float C0 = Ey * (c1a * c2a), C1 = Ey * (c0a * c2a), C2 = Ey * (c0a * c1a);
          float D0 = d1b * d2b,        D1 = d0b * d2b,        D2 = d0b * d1b;
          float n0y = tfloor(__fdividef(C0 - D0, C0 + D0));
          float n1y = tfloor(__fdividef(C1 - D1, C1 + D1));
          float n2y = tfloor(__fdividef(C2 - D2, C2 + D2));
          sT[s0] = make_float2(n0x, n0y);
          sT[s1] = make_float2(n1x, n1y);
          sT[s2] = make_float2(n2x, n2y);
        }
      }
    }
    __syncthreads();
    // ---- pass 2: per-check products (parity factor from register) ----
    {
      float px = qpar0.x, py = qpar0.y;
      for (int e = beg0; e < end0 - 1; ++e) { float2 tt = sT[e]; px *= tt.x; py *= tt.y; }
      sP[tid] = make_float2(px, py);
      if (c1ok) {
        float qx = qpar1.x, qy = qpar1.y;
        for (int e = beg1; e < end1 - 1; ++e) { float2 tt = sT[e]; qx *= tt.x; qy *= tt.y; }
        sP[tid + TB] = make_float2(qx, qy);
      }
    }
    __syncthreads();
  }

  // ---- decide: additive log form (once) ----
  int cw0 = pairId * 2;
  float* o0 = out + (size_t)ncw * KK + (size_t)cw0 * KK;
  float* o1 = o0 + KK;
  #pragma unroll
  for (int i = 0; i < 2; ++i) {
    if (iok[i]) {
      int n = tid + TB * i;
      int s0 = pk0[i] & 0xffff, c0 = ((unsigned)pk0[i]) >> 16;
      int s1 = pk1[i] & 0xffff, c1 = ((unsigned)pk1[i]) >> 16;
      int s2 = pk2[i] & 0xffff, c2 = ((unsigned)pk2[i]) >> 16;
      float2 P0 = sP[c0], P1 = sP[c1], P2 = sP[c2];
      float2 t0 = sT[s0], t1 = sT[s1], t2 = sT[s2];
      float2 L = Ln[i];
      float ax = L.x + atanh2c(P0.x, t0.x) + atanh2c(P1.x, t1.x) + atanh2c(P2.x, t2.x);
      float ay = L.y + atanh2c(P0.y, t0.y) + atanh2c(P1.y, t1.y) + atanh2c(P2.y, t2.y);
      o0[n] = (ax < 0.0f) ? 1.0f : 0.0f;
      o1[n] = (ay < 0.0f) ? 1.0f : 0.0f;
    }
  }
}

// ---------------- launcher ----------------
extern "C" void kernel_launch(void* const* d_in, const int* in_sizes, int n_in,
                              void* d_out, int out_size, void* d_ws, size_t ws_size,
                              hipStream_t stream) {
  const float* ebno = (const float*)d_in[1];
  const int*   b    = (const int*)d_in[2];
  const int*   P    = (const int*)d_in[3];
  const int*   cn   = (const int*)d_in[4];
  const int*   vn   = (const int*)d_in[5];
  const float* h_re = (const float*)d_in[6];
  const float* h_im = (const float*)d_in[7];
  const float* nre  = (const float*)d_in[8];
  const float* nim  = (const float*)d_in[9];
  float* out = (float*)d_out;

  int E     = in_sizes[4];
  int batch = in_sizes[2] / (4 * KK);
  int ncw   = batch * 4;
  int T     = batch * NSYM;

  char* ws = (char*)d_ws;
  size_t off = 0;
  auto alloc = [&](size_t bytes) -> void* {
    void* p = ws + off;
    off += (bytes + 255) & ~(size_t)255;
    return p;
  };
  float*    Lch3   = (float*)alloc((size_t)NNODES * ncw * 4);
  unsigned* Ppack  = (unsigned*)alloc((size_t)MM * 16 * 4);
  unsigned* bpack  = (unsigned*)alloc((size_t)ncw * 16 * 4);
  int*      coff   = (int*)alloc((size_t)(MM + 1) * 4);
  int*      cinfo  = (int*)alloc((size_t)EMAX * 4);
  int*      vlist  = (int*)alloc((size_t)NNODES * MAXVDEG * 4);
  double*   nobuf  = (double*)alloc(2 * 8);
  (void)ws_size; (void)n_in; (void)out_size;

  int packItems  = MM * 16 + ncw * 16;
  int packBlocks = (packItems + 511) / 512;
  int bfBlocks   = (ncw * KK + 511) / 512;
  int setupGrid  = 1 + packBlocks + bfBlocks;

  k_setup<<<dim3(setupGrid), dim3(512), 0, stream>>>(cn, vn, E, ebno, P, b, ncw,
                                                     cinfo, vlist, coff, nobuf,
                                                     Ppack, bpack, out, packBlocks);
  k_lmmse<<<dim3((T + TB - 1) / TB), dim3(TB), 0, stream>>>(h_re, h_im, nre, nim, nobuf,
                                                            bpack, Ppack, Lch3, T, ncw);
  k_bp<<<dim3(ncw / 2), dim3(TB), 0, stream>>>(Lch3, vlist, coff, cinfo, out, E, ncw);
}

// Round 13
// 182.544 us; speedup vs baseline: 1.4694x; 1.0240x over previous
//
#include <hip/hip_runtime.h>
#include <math.h>

// Problem constants (from reference)
#define KK     500   // info bits
#define MM     500   // parity checks
#define NNODES 1000  // N = K + M variable nodes
#define NSYM   250   // N / BPS
#define NITERS 5
#define MAXVDEG 4    // info vars degree exactly 3 (row weight of P), parity vars 1
#define EMAX   2048  // E = 2000 edges
#define TB     256
#define LTB    64    // k_lmmse block size (1 wave) for scheduling granularity

// ---------------- setup: graph build + bit packing + bf output -------------
// Slot layout per check c: info edges in coff[c]..coff[c+1]-2 (atomic order),
// the single parity edge (var >= KK) pinned to coff[c+1]-1 so the BP product
// loop can skip it and use a register-cached constant instead.
__global__ void __launch_bounds__(512)
k_setup(const int* __restrict__ cn, const int* __restrict__ vn, int E,
        const float* __restrict__ ebno, const int* __restrict__ P,
        const int* __restrict__ b, int ncw,
        int* __restrict__ cinfo, int* __restrict__ vlist, int* __restrict__ coff,
        double* __restrict__ nobuf, unsigned* __restrict__ Ppack,
        unsigned* __restrict__ bpack, float* __restrict__ out, int packBlocks) {
  __shared__ int sdeg[512];
  __shared__ int ssc[512];
  __shared__ int scur[512];
  __shared__ int svc[NNODES];
  int tid = threadIdx.x;
  int bx = blockIdx.x;

  if (bx == 0) {
    sdeg[tid] = 0;
    for (int n = tid; n < NNODES; n += 512) svc[n] = 0;
    __syncthreads();
    for (int e = tid; e < E; e += 512) atomicAdd(&sdeg[cn[e]], 1);
    __syncthreads();
    int v = sdeg[tid];
    ssc[tid] = v;
    __syncthreads();
    for (int o = 1; o < 512; o <<= 1) {
      int x = (tid >= o) ? ssc[tid - o] : 0;
      __syncthreads();
      ssc[tid] += x;
      __syncthreads();
    }
    int excl = ssc[tid] - v;
    scur[tid] = excl;
    if (tid < MM) {
      coff[tid] = excl;
      if (tid == MM - 1) coff[MM] = ssc[tid];
    }
    __syncthreads();
    for (int e = tid; e < E; e += 512) {
      int c = cn[e], n = vn[e];
      int slot;
      if (n >= KK) {
        slot = ssc[c] - 1;               // parity edge -> last slot of check c
      } else {
        slot = atomicAdd(&scur[c], 1);   // info edges fill coff[c]..coff[c+1]-2
      }
      cinfo[slot] = (c << 16) | n;
      if (n < KK) {
        int t = atomicAdd(&svc[n], 1);
        if (t < MAXVDEG) vlist[n * MAXVDEG + t] = slot;
      }
    }
    if (tid == 0) {
      double no = 1.0 / (pow(10.0, (double)ebno[0] * 0.1) * 2.0);  // BPS*RATE = 2
      nobuf[0] = no;
      nobuf[1] = sqrt(no * 0.5);
    }
    return;
  }

  if (bx <= packBlocks) {
    int id = (bx - 1) * 512 + tid;
    if (id < MM * 16) {
      int j = id >> 4, w = id & 15;
      unsigned word = 0u;
      int base = w * 32;
      for (int bit = 0; bit < 32; ++bit) {
        int i = base + bit;
        if (i < KK && P[i * MM + j] != 0) word |= (1u << bit);
      }
      Ppack[j * 16 + w] = word;
    } else {
      int id2 = id - MM * 16;
      if (id2 < ncw * 16) {
        int cw = id2 >> 4, w = id2 & 15;
        unsigned word = 0u;
        int base = w * 32;
        for (int bit = 0; bit < 32; ++bit) {
          int i = base + bit;
          if (i < KK && b[cw * KK + i] != 0) word |= (1u << bit);
        }
        bpack[cw * 16 + w] = word;
      }
    }
    return;
  }

  int id = (bx - 1 - packBlocks) * 512 + tid;
  if (id < ncw * KK) out[id] = (float)b[id];
}

// ---------------- 16-QAM constellation (fp64 for TX symbol) ----------------
__device__ __forceinline__ void qam_point(int p, double& re, double& im) {
  const double s = 0.31622776601683794;  // 1/sqrt(10)
  int b0 = (p >> 3) & 1, b1 = (p >> 2) & 1, b2 = (p >> 1) & 1, b3 = p & 1;
  re = (double)((1 - 2 * b0) * (2 - (1 - 2 * b2))) * s;
  im = (double)((1 - 2 * b1) * (2 - (1 - 2 * b3))) * s;
}

// ---------------- channel + LMMSE + max-log LLR --------------------------
// Round-12 profile: only ~3.8 waves/SIMD of total work exist (T=250k), so
// per-thread SERIAL latency sets runtime (VALUBusy 24%).  This version cuts
// the chain: rsqrt-based Cholesky (solves only ever use 1/L_jj -> no fp64
// sqrt or divide anywhere in the factorization) and fp32 demap ratios
// (reference computes x_hat / no_eff in fp32 anyway).
__global__ void __launch_bounds__(LTB, 1)
k_lmmse(const float* __restrict__ h_re, const float* __restrict__ h_im,
        const float* __restrict__ n_re, const float* __restrict__ n_im,
        const double* __restrict__ nobuf,
        const unsigned* __restrict__ bpack, const unsigned* __restrict__ Ppack,
        float* __restrict__ Lch3, int T, int ncw) {
  int t = blockIdx.x * blockDim.x + threadIdx.x;
  if (t >= T) return;
  int bt = t / NSYM, s = t - bt * NSYM;

  double no = nobuf[0];
  double sq = nobuf[1];
  const double is2 = 0.7071067811865475244;  // 1/sqrt(2)

  double Hr[4][4], Hi[4][4];
  {
    const float4* hr4 = (const float4*)h_re;
    const float4* hi4 = (const float4*)h_im;
    #pragma unroll
    for (int i = 0; i < 4; ++i) {
      float4 a = hr4[t * 4 + i], c = hi4[t * 4 + i];
      Hr[i][0] = (double)a.x * is2; Hr[i][1] = (double)a.y * is2;
      Hr[i][2] = (double)a.z * is2; Hr[i][3] = (double)a.w * is2;
      Hi[i][0] = (double)c.x * is2; Hi[i][1] = (double)c.y * is2;
      Hi[i][2] = (double)c.z * is2; Hi[i][3] = (double)c.w * is2;
    }
  }

  // transmitted symbols: encode+map inline
  double xr[4], xi[4];
  #pragma unroll
  for (int ue = 0; ue < 4; ++ue) {
    const unsigned* bp = bpack + (bt * 4 + ue) * 16;
    int v = 0;
    #pragma unroll
    for (int k = 0; k < 4; ++k) {
      int n = 4 * s + k;
      int bit;
      if (n < KK) {
        bit = (bp[n >> 5] >> (n & 31)) & 1;
      } else {
        const unsigned* pp = Ppack + (n - KK) * 16;
        int cnt = 0;
        #pragma unroll
        for (int w = 0; w < 16; ++w) cnt += __popc(bp[w] & pp[w]);
        bit = cnt & 1;
      }
      v = (v << 1) | bit;  // MSB-first: weights 8,4,2,1
    }
    qam_point(v, xr[ue], xi[ue]);
  }

  // y = H x + w
  double yr[4], yi[4];
  {
    float4 wr = ((const float4*)n_re)[t];
    float4 wi = ((const float4*)n_im)[t];
    float wrv[4] = {wr.x, wr.y, wr.z, wr.w};
    float wiv[4] = {wi.x, wi.y, wi.z, wi.w};
    #pragma unroll
    for (int i = 0; i < 4; ++i) {
      double ar = (double)wrv[i] * sq;
      double ai = (double)wiv[i] * sq;
      #pragma unroll
      for (int j = 0; j < 4; ++j) {
        ar += Hr[i][j] * xr[j] - Hi[i][j] * xi[j];
        ai += Hr[i][j] * xi[j] + Hi[i][j] * xr[j];
      }
      yr[i] = ar; yi[i] = ai;
    }
  }

  // A = H H^H + no I, lower triangle, into scalars
  auto dotc = [&](int i, int j, double& ar, double& ai) {
    double r = 0.0, m = 0.0;
    #pragma unroll
    for (int k = 0; k < 4; ++k) {
      r += Hr[i][k] * Hr[j][k] + Hi[i][k] * Hi[j][k];
      m += Hi[i][k] * Hr[j][k] - Hr[i][k] * Hi[j][k];
    }
    ar = r; ai = m;
  };
  double a00, a11, a22, a33, dum;
  double a10r, a10i, a20r, a20i, a21r, a21i, a30r, a30i, a31r, a31i, a32r, a32i;
  dotc(0, 0, a00, dum);  a00 += no;
  dotc(1, 0, a10r, a10i);
  dotc(1, 1, a11, dum);  a11 += no;
  dotc(2, 0, a20r, a20i);
  dotc(2, 1, a21r, a21i);
  dotc(2, 2, a22, dum);  a22 += no;
  dotc(3, 0, a30r, a30i);
  dotc(3, 1, a31r, a31i);
  dotc(3, 2, a32r, a32i);
  dotc(3, 3, a33, dum);  a33 += no;

  // Cholesky in inverse-diagonal form: i_jj = rsqrt(d_jj); L_jj never formed.
  double i00 = rsqrt(a00);
  double L10r = a10r * i00, L10i = a10i * i00;
  double L20r = a20r * i00, L20i = a20i * i00;
  double L30r = a30r * i00, L30i = a30i * i00;
  double d11 = a11 - (L10r * L10r + L10i * L10i);
  double i11 = rsqrt(d11);
  double L21r = (a21r - (L20r * L10r + L20i * L10i)) * i11;
  double L21i = (a21i - (L20i * L10r - L20r * L10i)) * i11;
  double L31r = (a31r - (L30r * L10r + L30i * L10i)) * i11;
  double L31i = (a31i - (L30i * L10r - L30r * L10i)) * i11;
  double d22 = a22 - (L20r * L20r + L20i * L20i) - (L21r * L21r + L21i * L21i);
  double i22 = rsqrt(d22);
  double L32r = (a32r - (L30r * L20r + L30i * L20i) - (L31r * L21r + L31i * L21i)) * i22;
  double L32i = (a32i - (L30i * L20r - L30r * L20i) - (L31i * L21r - L31r * L21i)) * i22;
  double d33 = a33 - (L30r * L30r + L30i * L30i) - (L31r * L31r + L31i * L31i)
                   - (L32r * L32r + L32i * L32i);
  double i33 = rsqrt(d33);

  // forward solve: U = L^{-1} H (in place on H), v = L^{-1} y (in place on y)
  #pragma unroll
  for (int j = 0; j < 4; ++j) {
    double u0r = Hr[0][j] * i00,               u0i = Hi[0][j] * i00;
    double u1r = (Hr[1][j] - (L10r * u0r - L10i * u0i)) * i11;
    double u1i = (Hi[1][j] - (L10r * u0i + L10i * u0r)) * i11;
    double u2r = (Hr[2][j] - (L20r * u0r - L20i * u0i) - (L21r * u1r - L21i * u1i)) * i22;
    double u2i = (Hi[2][j] - (L20r * u0i + L20i * u0r) - (L21r * u1i + L21i * u1r)) * i22;
    double u3r = (Hr[3][j] - (L30r * u0r - L30i * u0i) - (L31r * u1r - L31i * u1i)
                           - (L32r * u2r - L32i * u2i)) * i33;
    double u3i = (Hi[3][j] - (L30r * u0i + L30i * u0r) - (L31r * u1i + L31i * u1r)
                           - (L32r * u2i + L32i * u2r)) * i33;
    Hr[0][j] = u0r; Hi[0][j] = u0i; Hr[1][j] = u1r; Hi[1][j] = u1i;
    Hr[2][j] = u2r; Hi[2][j] = u2i; Hr[3][j] = u3r; Hi[3][j] = u3i;
  }
  {
    double v0r = yr[0] * i00,               v0i = yi[0] * i00;
    double v1r = (yr[1] - (L10r * v0r - L10i * v0i)) * i11;
    double v1i = (yi[1] - (L10r * v0i + L10i * v0r)) * i11;
    double v2r = (yr[2] - (L20r * v0r - L20i * v0i) - (L21r * v1r - L21i * v1i)) * i22;
    double v2i = (yi[2] - (L20r * v0i + L20i * v0r) - (L21r * v1i + L21i * v1r)) * i22;
    double v3r = (yr[3] - (L30r * v0r - L30i * v0i) - (L31r * v1r - L31i * v1i)
                        - (L32r * v2r - L32i * v2i)) * i33;
    double v3i = (yi[3] - (L30r * v0i + L30i * v0r) - (L31r * v1i + L31i * v1r)
                        - (L32r * v2i + L32i * v2r)) * i33;
    yr[0] = v0r; yi[0] = v0i; yr[1] = v1r; yi[1] = v1i;
    yr[2] = v2r; yi[2] = v2i; yr[3] = v3r; yi[3] = v3i;
  }

  // fp32 16-QAM table
  const float PRT[16] = { 0.31622776601683794f, 0.31622776601683794f, 0.9486832980505138f, 0.9486832980505138f,
                          0.31622776601683794f, 0.31622776601683794f, 0.9486832980505138f, 0.9486832980505138f,
                         -0.31622776601683794f,-0.31622776601683794f,-0.9486832980505138f,-0.9486832980505138f,
                         -0.31622776601683794f,-0.31622776601683794f,-0.9486832980505138f,-0.9486832980505138f };
  const float PIT[16] = { 0.31622776601683794f, 0.9486832980505138f, 0.31622776601683794f, 0.9486832980505138f,
                         -0.31622776601683794f,-0.9486832980505138f,-0.31622776601683794f,-0.9486832980505138f,
                          0.31622776601683794f, 0.9486832980505138f, 0.31622776601683794f, 0.9486832980505138f,
                         -0.31622776601683794f,-0.9486832980505138f,-0.31622776601683794f,-0.9486832980505138f };

  float llr[4][4];  // [bit k][ue j]
  #pragma unroll
  for (int j = 0; j < 4; ++j) {
    double dj = 0.0, rr = 0.0, ri = 0.0;
    #pragma unroll
    for (int i = 0; i < 4; ++i) {
      dj += Hr[i][j] * Hr[i][j] + Hi[i][j] * Hi[i][j];
      rr += Hr[i][j] * yr[i] + Hi[i][j] * yi[i];
      ri += Hr[i][j] * yi[i] - Hi[i][j] * yr[i];
    }
    // fp32 ratios (reference is fp32 here); 1-dj subtracted in fp64 first.
    // d < 1 - no/lambda strictly, so no cancellation hazard.
    float djf = (float)dj;
    float rdj = __fdividef(1.0f, djf);
    float xhr = (float)rr * rdj, xhi = (float)ri * rdj;
    float gap = (float)(1.0 - dj);
    float inoe = __fdividef(djf, fmaxf(gap, djf * 1e-12f));

    float m0[4] = {-1e30f, -1e30f, -1e30f, -1e30f};
    float m1[4] = {-1e30f, -1e30f, -1e30f, -1e30f};
    #pragma unroll
    for (int p = 0; p < 16; ++p) {
      float dr = xhr - PRT[p], di = xhi - PIT[p];
      float met = -(dr * dr + di * di) * inoe;
      #pragma unroll
      for (int k = 0; k < 4; ++k) {
        if ((p >> (3 - k)) & 1) m1[k] = fmaxf(m1[k], met);
        else                    m0[k] = fmaxf(m0[k], met);
      }
    }
    #pragma unroll
    for (int k = 0; k < 4; ++k) llr[k][j] = m0[k] - m1[k];
  }

  // store: plane 0 = ue{0,1}, plane 1 = ue{2,3}
  float2* pl0 = (float2*)(Lch3 + (size_t)bt * (NNODES * 4));
  float2* pl1 = pl0 + NNODES;
  #pragma unroll
  for (int k = 0; k < 4; ++k) {
    int node = 4 * s + k;
    pl0[node] = make_float2(llr[k][0], llr[k][1]);
    pl1[node] = make_float2(llr[k][2], llr[k][3]);
  }
}

// ---------------- fused LDS-resident BP decoder, 2 codewords / block --------
// Division-free pass-1: (A-B)/(A+B) invariant under common scale; factor
// pairs scaled by their own t (a' = t + Pc, b' = t - Pc).  Parity edges
// (one per check, constant t) factored into a register (qpar); product loop
// runs [beg, end-1).
__device__ __forceinline__ float tanh_half(float m) {
  float mc = fminf(fmaxf(m, -19.8f), 19.8f);
  float e = __expf(mc);
  float t = 1.0f - __fdividef(2.0f, e + 1.0f);
  return (t >= 0.0f) ? fmaxf(t, 1e-7f) : fminf(t, -1e-7f);
}
__device__ __forceinline__ float pclip(float P, float t) {
  // t * clip(P/t, +-0.999999), computed without dividing
  return copysignf(fminf(fabsf(P), 0.999999f * fabsf(t)), P);
}
__device__ __forceinline__ float tfloor(float t) {
  return (t >= 0.0f) ? fmaxf(t, 1e-7f) : fminf(t, -1e-7f);
}
__device__ __forceinline__ float atanh2c(float P, float t) {
  float r = __fdividef(P, t);
  r = fminf(fmaxf(r, -0.999999f), 0.999999f);
  return __logf(__fdividef(1.0f + r, 1.0f - r));
}

__global__ void __launch_bounds__(256) k_bp(const float* __restrict__ Lch3,
                                            const int* __restrict__ vlist,
                                            const int* __restrict__ coff,
                                            const int* __restrict__ cinfo,
                                            float* __restrict__ out, int E, int ncw) {
  __shared__ float2 sT[EMAX];   // tanh(v2c/2) per info-edge slot (16 KB)
  __shared__ float2 sP[512];    // per-check product of tanh (4 KB)

  int tid = threadIdx.x;
  int pairId = blockIdx.x;  // = bt*2 + plane; codewords 2*pairId, 2*pairId+1

  const float2* src = (const float2*)(Lch3 + (size_t)pairId * (NNODES * 2));

  // own info-node state in registers
  float2 Ln[2], En[2];
  int pk0[2], pk1[2], pk2[2]; bool iok[2];
  #pragma unroll
  for (int i = 0; i < 2; ++i) {
    int n = tid + TB * i;
    iok[i] = n < KK;
    Ln[i] = make_float2(0.f, 0.f);
    En[i] = make_float2(1.f, 1.f);
    pk0[i] = pk1[i] = pk2[i] = 0;
    if (iok[i]) {
      float2 L = src[n];
      Ln[i] = L;
      En[i] = make_float2(__expf(fminf(fmaxf(L.x, -55.f), 55.f)),
                          __expf(fminf(fmaxf(L.y, -55.f), 55.f)));
      int s0 = vlist[n * MAXVDEG], s1 = vlist[n * MAXVDEG + 1], s2 = vlist[n * MAXVDEG + 2];
      pk0[i] = (cinfo[s0] & 0xffff0000) | s0;
      pk1[i] = (cinfo[s1] & 0xffff0000) | s1;
      pk2[i] = (cinfo[s2] & 0xffff0000) | s2;
    }
  }
  // per-check constant: tanh of the parity-node LLR (check c <-> parity var KK+c)
  float2 qpar0, qpar1;
  {
    float2 Lp0 = src[KK + tid];
    qpar0 = make_float2(tanh_half(Lp0.x), tanh_half(Lp0.y));
  }
  bool c1ok = (tid + TB) < MM;
  if (c1ok) {
    float2 Lp1 = src[KK + tid + TB];
    qpar1 = make_float2(tanh_half(Lp1.x), tanh_half(Lp1.y));
  } else {
    qpar1 = make_float2(1.f, 1.f);
  }
  int beg0 = coff[tid], end0 = coff[tid + 1];
  int beg1 = c1ok ? coff[tid + TB] : 0;
  int end1 = c1ok ? coff[tid + TB + 1] : 0;
  // no barrier needed: first sT reads happen in pass 2, after the in-loop barrier

  for (int it = 0; it < NITERS; ++it) {
    // ---- pass 1: info-node var update ----
    if (it == 0) {
      #pragma unroll
      for (int i = 0; i < 2; ++i) {
        if (iok[i]) {
          float2 t = make_float2(tanh_half(Ln[i].x), tanh_half(Ln[i].y));
          sT[pk0[i] & 0xffff] = t;
          sT[pk1[i] & 0xffff] = t;
          sT[pk2[i] & 0xffff] = t;
        }
      }
    } else {
      #pragma unroll
      for (int i = 0; i < 2; ++i) {
        if (iok[i]) {
          int s0 = pk0[i] & 0xffff, c0 = ((unsigned)pk0[i]) >> 16;
          int s1 = pk1[i] & 0xffff, c1 = ((unsigned)pk1[i]) >> 16;
          int s2 = pk2[i] & 0xffff, c2 = ((unsigned)pk2[i]) >> 16;
          float2 P0 = sP[c0], P1 = sP[c1], P2 = sP[c2];
          float2 t0 = sT[s0], t1 = sT[s1], t2 = sT[s2];
          // lane x
          float p0 = pclip(P0.x, t0.x), p1 = pclip(P1.x, t1.x), p2 = pclip(P2.x, t2.x);
          float a0 = t0.x + p0, a1 = t1.x + p1, a2 = t2.x + p2;
          float b0 = t0.x - p0, b1 = t1.x - p1, b2 = t2.x - p2;
          float Ex = En[i].x;
          float A0 = Ex * (a1 * a2), A1 = Ex * (a0 * a2), A2 = Ex * (a0 * a1);
          float B0 = b1 * b2,        B1 = b0 * b2,        B2 = b0 * b1;
          float n0x = tfloor(__fdividef(A0 - B0, A0 + B0));
          float n1x = tfloor(__fdividef(A1 - B1, A1 + B1));
          float n2x = tfloor(__fdividef(A2 - B2, A2 + B2));
          // lane y
          float q0 = pclip(P0.y, t0.y), q1 = pclip(P1.y, t1.y), q2 = pclip(P2.y, t2.y);
          float c0a = t0.y + q0, c1a = t1.y + q1, c2a = t2.y + q2;
          float d0b = t0.y - q0, d1b = t1.y - q1, d2b = t2.y - q2;
          float Ey = En[i].y;
          float C0 = Ey * (c1a * c2a), C1 = Ey * (c0a * c2a), C2 = Ey * (c0a * c1a);
          float D0 = d1b * d2b,        D1 = d0b * d2b,        D2 = d0b * d1b;
          float n0y = tfloor(__fdividef(C0 - D0, C0 + D0));
          float n1y = tfloor(__fdividef(C1 - D1, C1 + D1));
          float n2y = tfloor(__fdividef(C2 - D2, C2 + D2));
          sT[s0] = make_float2(n0x, n0y);
          sT[s1] = make_float2(n1x, n1y);
          sT[s2] = make_float2(n2x, n2y);
        }
      }
    }
    __syncthreads();
    // ---- pass 2: per-check products (parity factor from register) ----
    {
      float px = qpar0.x, py = qpar0.y;
      for (int e = beg0; e < end0 - 1; ++e) { float2 tt = sT[e]; px *= tt.x; py *= tt.y; }
      sP[tid] = make_float2(px, py);
      if (c1ok) {
        float qx = qpar1.x, qy = qpar1.y;
        for (int e = beg1; e < end1 - 1; ++e) { float2 tt = sT[e]; qx *= tt.x; qy *= tt.y; }
        sP[tid + TB] = make_float2(qx, qy);
      }
    }
    __syncthreads();
  }

  // ---- decide: additive log form (once) ----
  int cw0 = pairId * 2;
  float* o0 = out + (size_t)ncw * KK + (size_t)cw0 * KK;
  float* o1 = o0 + KK;
  #pragma unroll
  for (int i = 0; i < 2; ++i) {
    if (iok[i]) {
      int n = tid + TB * i;
      int s0 = pk0[i] & 0xffff, c0 = ((unsigned)pk0[i]) >> 16;
      int s1 = pk1[i] & 0xffff, c1 = ((unsigned)pk1[i]) >> 16;
      int s2 = pk2[i] & 0xffff, c2 = ((unsigned)pk2[i]) >> 16;
      float2 P0 = sP[c0], P1 = sP[c1], P2 = sP[c2];
      float2 t0 = sT[s0], t1 = sT[s1], t2 = sT[s2];
      float2 L = Ln[i];
      float ax = L.x + atanh2c(P0.x, t0.x) + atanh2c(P1.x, t1.x) + atanh2c(P2.x, t2.x);
      float ay = L.y + atanh2c(P0.y, t0.y) + atanh2c(P1.y, t1.y) + atanh2c(P2.y, t2.y);
      o0[n] = (ax < 0.0f) ? 1.0f : 0.0f;
      o1[n] = (ay < 0.0f) ? 1.0f : 0.0f;
    }
  }
}

// ---------------- launcher ----------------
extern "C" void kernel_launch(void* const* d_in, const int* in_sizes, int n_in,
                              void* d_out, int out_size, void* d_ws, size_t ws_size,
                              hipStream_t stream) {
  const float* ebno = (const float*)d_in[1];
  const int*   b    = (const int*)d_in[2];
  const int*   P    = (const int*)d_in[3];
  const int*   cn   = (const int*)d_in[4];
  const int*   vn   = (const int*)d_in[5];
  const float* h_re = (const float*)d_in[6];
  const float* h_im = (const float*)d_in[7];
  const float* nre  = (const float*)d_in[8];
  const float* nim  = (const float*)d_in[9];
  float* out = (float*)d_out;

  int E     = in_sizes[4];
  int batch = in_sizes[2] / (4 * KK);
  int ncw   = batch * 4;
  int T     = batch * NSYM;

  char* ws = (char*)d_ws;
  size_t off = 0;
  auto alloc = [&](size_t bytes) -> void* {
    void* p = ws + off;
    off += (bytes + 255) & ~(size_t)255;
    return p;
  };
  float*    Lch3   = (float*)alloc((size_t)NNODES * ncw * 4);
  unsigned* Ppack  = (unsigned*)alloc((size_t)MM * 16 * 4);
  unsigned* bpack  = (unsigned*)alloc((size_t)ncw * 16 * 4);
  int*      coff   = (int*)alloc((size_t)(MM + 1) * 4);
  int*      cinfo  = (int*)alloc((size_t)EMAX * 4);
  int*      vlist  = (int*)alloc((size_t)NNODES * MAXVDEG * 4);
  double*   nobuf  = (double*)alloc(2 * 8);
  (void)ws_size; (void)n_in; (void)out_size;

  int packItems  = MM * 16 + ncw * 16;
  int packBlocks = (packItems + 511) / 512;
  int bfBlocks   = (ncw * KK + 511) / 512;
  int setupGrid  = 1 + packBlocks + bfBlocks;

  k_setup<<<dim3(setupGrid), dim3(512), 0, stream>>>(cn, vn, E, ebno, P, b, ncw,
                                                     cinfo, vlist, coff, nobuf,
                                                     Ppack, bpack, out, packBlocks);
  k_lmmse<<<dim3((T + LTB - 1) / LTB), dim3(LTB), 0, stream>>>(h_re, h_im, nre, nim, nobuf,
                                                               bpack, Ppack, Lch3, T, ncw);
  k_bp<<<dim3(ncw / 2), dim3(TB), 0, stream>>>(Lch3, vlist, coff, cinfo, out, E, ncw);
}